// Round 5
// baseline (1519.629 us; speedup 1.0000x reference)
//
#include <hip/hip_runtime.h>
#include <hip/hip_bf16.h>

// B=512, S=64, IN=128, DM=256, H=8, HD=32, L=2, FF=1024, DO=64, E=8, K=2, GI=8192

typedef __attribute__((ext_vector_type(8))) short bf16x8;
typedef __attribute__((ext_vector_type(4))) float f32x4;

#define DEVINL __device__ __forceinline__
#define MFMA16(a, b, c) __builtin_amdgcn_mfma_f32_16x16x32_bf16((a), (b), (c), 0, 0, 0)

DEVINL float b2f(unsigned short u) {
    unsigned int i = ((unsigned int)u) << 16;
    float f; __builtin_memcpy(&f, &i, 4); return f;
}
DEVINL unsigned short f2b(float f) {
    unsigned int i; __builtin_memcpy(&i, &f, 4);
    unsigned int r = (i + 0x7FFFu + ((i >> 16) & 1u)) >> 16;  // RTN-even
    return (unsigned short)r;
}

// ---------------------------------------------------------------------------
__global__ void zero_cnt_kernel(int* __restrict__ cnt) {
    if (threadIdx.x < 8) cnt[threadIdx.x] = 0;
}

// ---------------------------------------------------------------------------
// convT: src fp32 [batch][R][C] -> dst bf16 [batch][C][R]  (B-operand layout)
__global__ __launch_bounds__(256) void convT_kernel(
    const float* __restrict__ src, short* __restrict__ dst, int R, int C, int total)
{
    int idx = blockIdx.x * 256 + threadIdx.x;
    if (idx >= total) return;
    int rc = R * C;
    int bM = idx / rc;
    int rem = idx - bM * rc;
    int c = rem / R;
    int r = rem - c * R;
    dst[idx] = (short)f2b(src[(size_t)bM * rc + (size_t)r * C + c]);
}

// ---------------------------------------------------------------------------
// gate: double-precision logits (stable top-2 vs numpy ref)
__global__ __launch_bounds__(256) void gate_kernel(
    const float* __restrict__ x, const float* __restrict__ Wg, const float* __restrict__ bg,
    int* __restrict__ cnt, int* __restrict__ rlist, float* __restrict__ wlist)
{
    const int b = blockIdx.x;
    const int tid = threadIdx.x;
    const int e8 = tid & 7;
    const int seg = tid >> 3;
    const float* gi = x + (size_t)b * 8192;
    double p = 0.0;
    for (int ii = 0; ii < 256; ++ii) {
        int i = seg * 256 + ii;
        p += (double)gi[i] * (double)Wg[i * 8 + e8];
    }
    p += __shfl_xor(p, 8, 64);
    p += __shfl_xor(p, 16, 64);
    p += __shfl_xor(p, 32, 64);
    __shared__ double wred[4 * 8];
    const int lane = tid & 63, w = tid >> 6;
    if (lane < 8) wred[w * 8 + lane] = p;
    __syncthreads();
    if (tid == 0) {
        double lg[8];
        for (int e = 0; e < 8; ++e)
            lg[e] = wred[e] + wred[8 + e] + wred[16 + e] + wred[24 + e] + (double)bg[e];
        int i1 = 0;
        for (int e = 1; e < 8; ++e) if (lg[e] > lg[i1]) i1 = e;
        int i2 = (i1 == 0) ? 1 : 0;
        for (int e = 0; e < 8; ++e) if (e != i1 && lg[e] > lg[i2]) i2 = e;
        double ex = exp(lg[i2] - lg[i1]);
        float w1 = (float)(1.0 / (1.0 + ex));
        float w2 = (float)(ex / (1.0 + ex));
        int p1 = atomicAdd(&cnt[i1], 1);
        rlist[i1 * 512 + p1] = b; wlist[i1 * 512 + p1] = w1;
        int p2 = atomicAdd(&cnt[i2], 1);
        rlist[i2 * 512 + p2] = b; wlist[i2 * 512 + p2] = w2;
    }
}

// ---------------------------------------------------------------------------
// resproj: 2 batch rows per block, 256 blocks
__global__ __launch_bounds__(256) void resproj_kernel(
    const float* __restrict__ x, const float* __restrict__ Wr, const float* __restrict__ br,
    float* __restrict__ acc_out)
{
    const int b0 = blockIdx.x * 2;
    const int tid = threadIdx.x;
    const int d = tid & 63;
    const int part = tid >> 6;
    float acc0 = 0.f, acc1 = 0.f;
    for (int ii = 0; ii < 2048; ++ii) {
        int i = part * 2048 + ii;
        float wv = Wr[i * 64 + d];
        acc0 += x[(size_t)b0 * 8192 + i] * wv;
        acc1 += x[(size_t)(b0 + 1) * 8192 + i] * wv;
    }
    __shared__ float rr[4][2][64];
    rr[part][0][d] = acc0;
    rr[part][1][d] = acc1;
    __syncthreads();
    if (tid < 128) {
        int k = tid >> 6, dd = tid & 63;
        float v = rr[0][k][dd] + rr[1][k][dd] + rr[2][k][dd] + rr[3][k][dd];
        acc_out[(b0 + k) * 64 + dd] = 0.1f * (v + br[dd]);
    }
}

// ---------------------------------------------------------------------------
// expert kernel — 512 threads / 8 waves / M-split pairs.
// Wave w = (rh = w>>2, cg = w&3) owns output rows [rh*32, +32) and cols
// [cg*64, +64) of every GEMM -> 2 waves/SIMD.
// ROUND 5: 512-thread blocks force total regs <= 256/wave; allocator splits
// ~128 AGPR (f32x4 accum) + ~120 arch. Rounds 3/4 HOISTED 64 arch regs of
// A-frags across phases -> arch demand > 120 -> 126MB scratch spills.
// Fix: NO cross-phase hoisting. Every GEMM phase is
//   for ct { load B[<=8]; for rt { load A[<=8] from LDS; MFMA } }
// A-frags re-read from LDS per col tile (LDS has headroom). Peak arch
// live ~84; AGPR peak ~96. Total ~190 << 256 -> nothing to spill.
// XCD pin: e = blockIdx&7 so each XCD's L2 holds one expert's weight image.
__global__ __launch_bounds__(512, 1) void expert_kernel(
    const float* __restrict__ x,
    const short* __restrict__ WinT, const float* __restrict__ bin_,
    const short* __restrict__ WqT,  const float* __restrict__ bq,
    const short* __restrict__ WkT,  const float* __restrict__ bk,
    const short* __restrict__ WvT,  const float* __restrict__ bv,
    const short* __restrict__ WoT,  const float* __restrict__ bo,
    const float* __restrict__ ln1g, const float* __restrict__ ln1b,
    const float* __restrict__ ln2g, const float* __restrict__ ln2b,
    const short* __restrict__ W1T,  const float* __restrict__ b1,
    const short* __restrict__ W2T,  const float* __restrict__ b2,
    const float* __restrict__ Wout, const float* __restrict__ bout,
    const int* __restrict__ cnt, const int* __restrict__ rlist,
    const float* __restrict__ wlist, float* __restrict__ acc_out)
{
    const int e = blockIdx.x & 7;          // XCD pin
    const int s = blockIdx.x >> 3;
    if (s >= cnt[e]) return;
    const int b   = rlist[e * 512 + s];
    const float wgt = wlist[e * 512 + s];
    const int tid = threadIdx.x;
    const int lane = tid & 63;
    const int wg  = __builtin_amdgcn_readfirstlane(tid >> 6);
    const int ln = lane & 15, quad = lane >> 4;
    const int cg = wg & 3;                 // col group: cols [cg*64, +64)
    const int rh = wg >> 2;                // row half:  rows [rh*32, +32)
    const int nb = cg * 64;
    const int r0 = rh * 32;

    // LDS: 33,792 + 96,256 + 2,048 + 2,048 = 134,144 B -> 1 block/CU (8 waves)
    __shared__ __align__(16) unsigned short hS[64 * 264];      // residual/av/LN out
    __shared__ __align__(16) unsigned short attnS[4 * 12032];  // per-pair attn | xS | tS
    __shared__ float redS[512];                                // LN cross-wave partials
    __shared__ float pooledS[512];                             // 2 row-half partials
    unsigned short* Qw  = attnS + cg * 12032;  // [64][40]
    unsigned short* Kw  = Qw + 2560;           // [64][40]
    unsigned short* VTw = Qw + 5120;           // [32][72]
    unsigned short* PSw = Qw + 7424;           // [64][72] (own buffer, no overlay)
    unsigned short* xS  = attnS;               // [64][136] (block-shared, P0/P1)

    // ---- P0: stage x[b] -> xS bf16 row-major ----
    {
        const float* xb = x + (size_t)b * 8192;
        #pragma unroll
        for (int i = 0; i < 16; ++i) {
            int id = tid + 512 * i;
            xS[(id >> 7) * 136 + (id & 127)] = f2b(xb[id]);
        }
    }
    __syncthreads();

    f32x4 hr[8];   // residual: wave's 32 rows x 64 cols, [rt*4+ct]

    // ---- P1: h0 = x @ Win + bin (K=128) ----
    {
        const short* BW = WinT + (size_t)e * 32768;
        const float* bp = bin_ + e * 256;
        #pragma unroll
        for (int ct = 0; ct < 4; ++ct) {
            bf16x8 Bf[4];
            #pragma unroll
            for (int kt = 0; kt < 4; ++kt)
                Bf[kt] = *(const bf16x8*)(BW + (size_t)(nb + ct * 16 + ln) * 128 + kt * 32 + quad * 8);
            const float bz = bp[nb + ct * 16 + ln];
            #pragma unroll
            for (int rt = 0; rt < 2; ++rt) {
                bf16x8 Af[4];
                #pragma unroll
                for (int kt = 0; kt < 4; ++kt)
                    Af[kt] = *(const bf16x8*)&xS[(r0 + rt * 16 + ln) * 136 + kt * 32 + quad * 8];
                f32x4 c = {bz, bz, bz, bz};
                #pragma unroll
                for (int kt = 0; kt < 4; ++kt) c = MFMA16(Af[kt], Bf[kt], c);
                hr[rt * 4 + ct] = c;
                #pragma unroll
                for (int i = 0; i < 4; ++i)
                    hS[(r0 + rt * 16 + quad * 4 + i) * 264 + nb + ct * 16 + ln] = f2b(c[i]);
            }
        }
    }
    __syncthreads();

    // LayerNorm over acc; cross-wave via redS; writes hr + hS.
    auto LN = [&](f32x4* a, const float* g, const float* bb) {
        #pragma unroll
        for (int rt = 0; rt < 2; ++rt)
            #pragma unroll
            for (int i = 0; i < 4; ++i) {
                float s1 = 0.f, s2 = 0.f;
                #pragma unroll
                for (int ct = 0; ct < 4; ++ct) { float v = a[rt * 4 + ct][i]; s1 += v; s2 += v * v; }
                s1 += __shfl_xor(s1, 1); s1 += __shfl_xor(s1, 2);
                s1 += __shfl_xor(s1, 4); s1 += __shfl_xor(s1, 8);
                s2 += __shfl_xor(s2, 1); s2 += __shfl_xor(s2, 2);
                s2 += __shfl_xor(s2, 4); s2 += __shfl_xor(s2, 8);
                if (ln == 0) {
                    int row = r0 + rt * 16 + quad * 4 + i;
                    redS[row * 8 + cg * 2] = s1;
                    redS[row * 8 + cg * 2 + 1] = s2;
                }
            }
        __syncthreads();
        float gv[4], bv2[4];
        #pragma unroll
        for (int ct = 0; ct < 4; ++ct) { gv[ct] = g[nb + ct * 16 + ln]; bv2[ct] = bb[nb + ct * 16 + ln]; }
        #pragma unroll
        for (int rt = 0; rt < 2; ++rt)
            #pragma unroll
            for (int i = 0; i < 4; ++i) {
                int row = r0 + rt * 16 + quad * 4 + i;
                float S1 = redS[row * 8 + 0] + redS[row * 8 + 2] + redS[row * 8 + 4] + redS[row * 8 + 6];
                float S2 = redS[row * 8 + 1] + redS[row * 8 + 3] + redS[row * 8 + 5] + redS[row * 8 + 7];
                float m_ = S1 * (1.f / 256.f);
                float rstd = rsqrtf(S2 * (1.f / 256.f) - m_ * m_ + 1e-5f);
                #pragma unroll
                for (int ct = 0; ct < 4; ++ct) {
                    float v = (a[rt * 4 + ct][i] - m_) * rstd * gv[ct] + bv2[ct];
                    hr[rt * 4 + ct][i] = v;
                    hS[row * 264 + nb + ct * 16 + ln] = f2b(v);
                }
            }
        __syncthreads();
    };

    for (int l = 0; l < 2; ++l) {
        const int el = e * 2 + l;
        const short* WqE = WqT + (size_t)el * 65536;
        const short* WkE = WkT + (size_t)el * 65536;
        const short* WvE = WvT + (size_t)el * 65536;
        const short* WoE = WoT + (size_t)el * 65536;
        const short* W1E = W1T + (size_t)el * 262144;
        const short* W2E = W2T + (size_t)el * 262144;
        const float* bq_p = bq + el * 256;
        const float* bk_p = bk + el * 256;
        const float* bv_p = bv + el * 256;
        const float* bo_p = bo + el * 256;

        f32x4 avr[8];   // both heads' av: [hp*4 + rt*2 + ct2]

        // ---- QKV + attention: pair (rh=0,cg)+(rh=1,cg) shares slot cg ----
        for (int hp = 0; hp < 2; ++hp) {
            const int hb = nb + hp * 32;   // head (2*cg+hp) col base

            // No A-hoisting: A-frags re-read from hS per ct2 (arch-pressure fix).
            auto qkv = [&](const short* WB, const float* bbp, unsigned short* dQK, int isV) {
                #pragma unroll
                for (int ct2 = 0; ct2 < 2; ++ct2) {
                    bf16x8 Bq[8];
                    #pragma unroll
                    for (int kt = 0; kt < 8; ++kt)
                        Bq[kt] = *(const bf16x8*)(WB + (size_t)(hb + ct2 * 16 + ln) * 256 + kt * 32 + quad * 8);
                    const float bz2 = bbp[hb + ct2 * 16 + ln];
                    #pragma unroll
                    for (int rt = 0; rt < 2; ++rt) {
                        bf16x8 Af[8];
                        #pragma unroll
                        for (int kt = 0; kt < 8; ++kt)
                            Af[kt] = *(const bf16x8*)&hS[(r0 + rt * 16 + ln) * 264 + kt * 32 + quad * 8];
                        f32x4 c = {bz2, bz2, bz2, bz2};
                        #pragma unroll
                        for (int kt = 0; kt < 8; ++kt) c = MFMA16(Af[kt], Bq[kt], c);
                        if (!isV) {
                            #pragma unroll
                            for (int i = 0; i < 4; ++i)
                                dQK[(r0 + rt * 16 + quad * 4 + i) * 40 + ct2 * 16 + ln] = f2b(c[i]);
                        } else {
                            #pragma unroll
                            for (int i = 0; i < 4; ++i)
                                VTw[(ct2 * 16 + ln) * 72 + r0 + rt * 16 + quad * 4 + i] = f2b(c[i]);
                        }
                    }
                }
            };
            qkv(WqE, bq_p, Qw, 0);
            qkv(WkE, bk_p, Kw, 0);
            qkv(WvE, bv_p, nullptr, 1);
            __syncthreads();   // pair's K/VT rows complete (also: hS reads done)

            // --- S = Q K^T (M=32 own rows, N=64, K=32) ---
            f32x4 sc[8];
            {
                bf16x8 Bk[4];
                #pragma unroll
                for (int ck = 0; ck < 4; ++ck)
                    Bk[ck] = *(const bf16x8*)&Kw[(ck * 16 + ln) * 40 + quad * 8];
                #pragma unroll
                for (int rt = 0; rt < 2; ++rt) {
                    bf16x8 Aq = *(const bf16x8*)&Qw[(r0 + rt * 16 + ln) * 40 + quad * 8];
                    #pragma unroll
                    for (int ck = 0; ck < 4; ++ck) {
                        f32x4 z = {0.f, 0.f, 0.f, 0.f};
                        sc[rt * 4 + ck] = MFMA16(Aq, Bk[ck], z);
                    }
                }
            }
            // --- softmax per row (in-wave, 16-lane groups) ---
            const float sscale = 0.17677669529663687f;  // 1/sqrt(32)
            #pragma unroll
            for (int t = 0; t < 8; ++t)
                #pragma unroll
                for (int i = 0; i < 4; ++i) sc[t][i] *= sscale;
            #pragma unroll
            for (int rt = 0; rt < 2; ++rt)
                #pragma unroll
                for (int i = 0; i < 4; ++i) {
                    float m_ = fmaxf(fmaxf(sc[rt * 4 + 0][i], sc[rt * 4 + 1][i]),
                                     fmaxf(sc[rt * 4 + 2][i], sc[rt * 4 + 3][i]));
                    m_ = fmaxf(m_, __shfl_xor(m_, 1));
                    m_ = fmaxf(m_, __shfl_xor(m_, 2));
                    m_ = fmaxf(m_, __shfl_xor(m_, 4));
                    m_ = fmaxf(m_, __shfl_xor(m_, 8));
                    float s_ = 0.f;
                    #pragma unroll
                    for (int ck = 0; ck < 4; ++ck) {
                        sc[rt * 4 + ck][i] = __expf(sc[rt * 4 + ck][i] - m_);
                        s_ += sc[rt * 4 + ck][i];
                    }
                    s_ += __shfl_xor(s_, 1); s_ += __shfl_xor(s_, 2);
                    s_ += __shfl_xor(s_, 4); s_ += __shfl_xor(s_, 8);
                    float inv = 1.f / s_;
                    int row = r0 + rt * 16 + quad * 4 + i;
                    #pragma unroll
                    for (int ck = 0; ck < 4; ++ck)
                        PSw[row * 72 + ck * 16 + ln] = f2b(sc[rt * 4 + ck][i] * inv);
                }

            // --- av = P @ V (M=32 own rows, N=32, K=64); PS rows are own-wave ---
            {
                #pragma unroll
                for (int ct2 = 0; ct2 < 2; ++ct2) {
                    bf16x8 Bv[2];
                    #pragma unroll
                    for (int kt2 = 0; kt2 < 2; ++kt2)
                        Bv[kt2] = *(const bf16x8*)&VTw[(ct2 * 16 + ln) * 72 + kt2 * 32 + quad * 8];
                    #pragma unroll
                    for (int rt = 0; rt < 2; ++rt) {
                        bf16x8 Ap[2];
                        #pragma unroll
                        for (int kt2 = 0; kt2 < 2; ++kt2)
                            Ap[kt2] = *(const bf16x8*)&PSw[(r0 + rt * 16 + ln) * 72 + kt2 * 32 + quad * 8];
                        f32x4 c = {0.f, 0.f, 0.f, 0.f};
                        #pragma unroll
                        for (int kt2 = 0; kt2 < 2; ++kt2) c = MFMA16(Ap[kt2], Bv[kt2], c);
                        avr[hp * 4 + rt * 2 + ct2] = c;
                    }
                }
            }
            if (hp == 0) __syncthreads();  // partner done reading Kw/VTw before hp=1 overwrites
        }

        // write av (wave's 32 rows x 64 cols) -> hS; hS(h) reads all done at last barrier
        #pragma unroll
        for (int hp = 0; hp < 2; ++hp)
            #pragma unroll
            for (int rt = 0; rt < 2; ++rt)
                #pragma unroll
                for (int ct2 = 0; ct2 < 2; ++ct2)
                    #pragma unroll
                    for (int i = 0; i < 4; ++i)
                        hS[(r0 + rt * 16 + quad * 4 + i) * 264 + nb + hp * 32 + ct2 * 16 + ln]
                            = f2b(avr[hp * 4 + rt * 2 + ct2][i]);
        __syncthreads();

        // ---- O-proj: oacc = h + bo + av @ Wo (K=256); no hoisting ----
        f32x4 oacc[8];
        #pragma unroll
        for (int rt = 0; rt < 2; ++rt)
            #pragma unroll
            for (int ct = 0; ct < 4; ++ct) {
                float bz = bo_p[nb + ct * 16 + ln];
                f32x4 t = hr[rt * 4 + ct];
                t[0] += bz; t[1] += bz; t[2] += bz; t[3] += bz;
                oacc[rt * 4 + ct] = t;
            }
        #pragma unroll
        for (int ct = 0; ct < 4; ++ct) {
            bf16x8 Bo[8];
            #pragma unroll
            for (int kt = 0; kt < 8; ++kt)
                Bo[kt] = *(const bf16x8*)(WoE + (size_t)(nb + ct * 16 + ln) * 256 + kt * 32 + quad * 8);
            #pragma unroll
            for (int rt = 0; rt < 2; ++rt) {
                bf16x8 Ao[8];
                #pragma unroll
                for (int kt = 0; kt < 8; ++kt)
                    Ao[kt] = *(const bf16x8*)&hS[(r0 + rt * 16 + ln) * 264 + kt * 32 + quad * 8];
                #pragma unroll
                for (int kt = 0; kt < 8; ++kt)
                    oacc[rt * 4 + ct] = MFMA16(Ao[kt], Bo[kt], oacc[rt * 4 + ct]);
            }
        }

        // ---- LN1 -> hr, hS ----
        LN(oacc, ln1g + el * 256, ln1b + el * 256);

        // ---- FF: 8 chunks of 128 FF cols, tS double-buffered (1 barrier/chunk) ----
        f32x4 facc[8];
        {
            const float* b2_p = b2 + el * 256;
            #pragma unroll
            for (int rt = 0; rt < 2; ++rt)
                #pragma unroll
                for (int ct = 0; ct < 4; ++ct) {
                    float bz = b2_p[nb + ct * 16 + ln];
                    f32x4 t = hr[rt * 4 + ct];
                    t[0] += bz; t[1] += bz; t[2] += bz; t[3] += bz;
                    facc[rt * 4 + ct] = t;
                }
        }
        const float* b1_p = b1 + el * 1024;
        for (int ch = 0; ch < 8; ++ch) {
            const int fb = ch * 128 + cg * 32;       // wave's 32 FF cols this chunk
            unsigned short* tC = attnS + (ch & 1) * 8704;   // [64][136] dbuf
            #pragma unroll
            for (int ct2 = 0; ct2 < 2; ++ct2) {
                bf16x8 B1c[8];
                #pragma unroll
                for (int kt = 0; kt < 8; ++kt)
                    B1c[kt] = *(const bf16x8*)(W1E + (size_t)(fb + ct2 * 16 + ln) * 256 + kt * 32 + quad * 8);
                const float bz2 = b1_p[fb + ct2 * 16 + ln];
                #pragma unroll
                for (int rt = 0; rt < 2; ++rt) {
                    bf16x8 Af[8];
                    #pragma unroll
                    for (int kt = 0; kt < 8; ++kt)
                        Af[kt] = *(const bf16x8*)&hS[(r0 + rt * 16 + ln) * 264 + kt * 32 + quad * 8];
                    f32x4 c = {bz2, bz2, bz2, bz2};
                    #pragma unroll
                    for (int kt = 0; kt < 8; ++kt) c = MFMA16(Af[kt], B1c[kt], c);
                    #pragma unroll
                    for (int i = 0; i < 4; ++i)
                        tC[(r0 + rt * 16 + quad * 4 + i) * 136 + cg * 32 + ct2 * 16 + ln]
                            = f2b(fmaxf(c[i], 0.f));
                }
            }
            __syncthreads();
            // W2 partial: K=128 (B loaded once per ct; A re-read per ct from tC)
            #pragma unroll
            for (int ct = 0; ct < 4; ++ct) {
                bf16x8 B2c[4];
                #pragma unroll
                for (int kt2 = 0; kt2 < 4; ++kt2)
                    B2c[kt2] = *(const bf16x8*)(W2E + (size_t)(nb + ct * 16 + ln) * 1024 + ch * 128 + kt2 * 32 + quad * 8);
                #pragma unroll
                for (int rt = 0; rt < 2; ++rt) {
                    bf16x8 At[4];
                    #pragma unroll
                    for (int kt2 = 0; kt2 < 4; ++kt2)
                        At[kt2] = *(const bf16x8*)&tC[(r0 + rt * 16 + ln) * 136 + kt2 * 32 + quad * 8];
                    #pragma unroll
                    for (int kt2 = 0; kt2 < 4; ++kt2)
                        facc[rt * 4 + ct] = MFMA16(At[kt2], B2c[kt2], facc[rt * 4 + ct]);
                }
            }
            // no barrier: next W1 writes the other tS buffer
        }

        // ---- LN2 -> hr, hS ----
        LN(facc, ln2g + el * 256, ln2b + el * 256);
    }

    // ---- pooling + Wout + weighted combine ----
    {
        #pragma unroll
        for (int ct = 0; ct < 4; ++ct) {
            float s_ = 0.f;
            #pragma unroll
            for (int rt = 0; rt < 2; ++rt)
                #pragma unroll
                for (int i = 0; i < 4; ++i) s_ += hr[rt * 4 + ct][i];
            s_ += __shfl_xor(s_, 16);
            s_ += __shfl_xor(s_, 32);
            if (quad == 0) pooledS[rh * 256 + nb + ct * 16 + ln] = s_;
        }
        __syncthreads();
        if (tid < 64) {
            const float* Wout_p = Wout + (size_t)e * (256 * 64);
            float o = bout[e * 64 + tid];
            for (int c = 0; c < 256; ++c)
                o += (pooledS[c] + pooledS[256 + c]) * (1.f / 64.f) * Wout_p[c * 64 + tid];
            atomicAdd(&acc_out[b * 64 + tid], wgt * o);
        }
    }
}

// ---------------------------------------------------------------------------
__global__ __launch_bounds__(64) void final_ln_kernel(
    const float* __restrict__ acc_out, const float* __restrict__ on_g,
    const float* __restrict__ on_b, float* __restrict__ out)
{
    const int b = blockIdx.x;
    const int d = threadIdx.x;
    float v = acc_out[b * 64 + d];
    float s1 = v, s2 = v * v;
    #pragma unroll
    for (int st = 1; st < 64; st <<= 1) {
        s1 += __shfl_xor(s1, st, 64);
        s2 += __shfl_xor(s2, st, 64);
    }
    float m   = s1 * (1.f / 64.f);
    float var = s2 * (1.f / 64.f) - m * m;
    float rstd = rsqrtf(var + 1e-5f);
    out[b * 64 + d] = (v - m) * rstd * on_g[d] + on_b[d];
}

// ---------------------------------------------------------------------------
extern "C" void kernel_launch(void* const* d_in, const int* in_sizes, int n_in,
                              void* d_out, int out_size, void* d_ws, size_t ws_size,
                              hipStream_t stream)
{
    (void)in_sizes; (void)n_in; (void)out_size; (void)ws_size;
    const float* x    = (const float*)d_in[0];
    const float* Win  = (const float*)d_in[1];
    const float* bin_ = (const float*)d_in[2];
    const float* Wq   = (const float*)d_in[3];
    const float* bq   = (const float*)d_in[4];
    const float* Wk   = (const float*)d_in[5];
    const float* bk   = (const float*)d_in[6];
    const float* Wv   = (const float*)d_in[7];
    const float* bv   = (const float*)d_in[8];
    const float* Wo   = (const float*)d_in[9];
    const float* bo   = (const float*)d_in[10];
    const float* ln1g = (const float*)d_in[11];
    const float* ln1b = (const float*)d_in[12];
    const float* ln2g = (const float*)d_in[13];
    const float* ln2b = (const float*)d_in[14];
    const float* W1   = (const float*)d_in[15];
    const float* b1   = (const float*)d_in[16];
    const float* W2   = (const float*)d_in[17];
    const float* b2   = (const float*)d_in[18];
    const float* Wout = (const float*)d_in[19];
    const float* bout = (const float*)d_in[20];
    const float* Wg   = (const float*)d_in[21];
    const float* bg   = (const float*)d_in[22];
    const float* Wr   = (const float*)d_in[23];
    const float* br   = (const float*)d_in[24];
    const float* on_g = (const float*)d_in[25];
    const float* on_b = (const float*)d_in[26];
    float* out = (float*)d_out;

    // workspace carve-up
    char* ws = (char*)d_ws;
    float* acc_out = (float*)ws;                         // 131,072 B
    int*   cnt     = (int*)(ws + 131072);
    int*   rlist   = (int*)(ws + 131200);                // 16,384 B
    float* wlist   = (float*)(ws + 147584);              // 16,384 B
    short* WinT    = (short*)(ws + 164096);              //   524,288 B
    short* WqT     = (short*)(ws + 688384);              // 2,097,152 B
    short* WkT     = (short*)(ws + 2785536);
    short* WvT     = (short*)(ws + 4882688);
    short* WoT     = (short*)(ws + 6979840);
    short* W1T     = (short*)(ws + 9076992);             // 8,388,608 B
    short* W2T     = (short*)(ws + 17465600);            // 8,388,608 B

    // weight transposition fp32 [R][C] -> bf16 [C][R]
    convT_kernel<<<1024, 256, 0, stream>>>(Win, WinT, 128, 256, 262144);
    convT_kernel<<<4096, 256, 0, stream>>>(Wq, WqT, 256, 256, 1048576);
    convT_kernel<<<4096, 256, 0, stream>>>(Wk, WkT, 256, 256, 1048576);
    convT_kernel<<<4096, 256, 0, stream>>>(Wv, WvT, 256, 256, 1048576);
    convT_kernel<<<4096, 256, 0, stream>>>(Wo, WoT, 256, 256, 1048576);
    convT_kernel<<<16384, 256, 0, stream>>>(W1, W1T, 256, 1024, 4194304);
    convT_kernel<<<16384, 256, 0, stream>>>(W2, W2T, 1024, 256, 4194304);

    zero_cnt_kernel<<<1, 64, 0, stream>>>(cnt);
    gate_kernel<<<512, 256, 0, stream>>>(x, Wg, bg, cnt, rlist, wlist);
    resproj_kernel<<<256, 256, 0, stream>>>(x, Wr, br, acc_out);
    expert_kernel<<<4096, 512, 0, stream>>>(x,
        WinT, bin_, WqT, bq, WkT, bk, WvT, bv, WoT, bo,
        ln1g, ln1b, ln2g, ln2b, W1T, b1, W2T, b2, Wout, bout,
        cnt, rlist, wlist, acc_out);
    final_ln_kernel<<<512, 64, 0, stream>>>(acc_out, on_g, on_b, out);
}

// Round 6
// 1460.725 us; speedup vs baseline: 1.0403x; 1.0403x over previous
//
#include <hip/hip_runtime.h>
#include <hip/hip_bf16.h>

// B=512, S=64, IN=128, DM=256, H=8, HD=32, L=2, FF=1024, DO=64, E=8, K=2, GI=8192

typedef __attribute__((ext_vector_type(8))) short bf16x8;
typedef __attribute__((ext_vector_type(4))) float f32x4;

#define DEVINL __device__ __forceinline__
#define MFMA16(a, b, c) __builtin_amdgcn_mfma_f32_16x16x32_bf16((a), (b), (c), 0, 0, 0)

DEVINL float b2f(unsigned short u) {
    unsigned int i = ((unsigned int)u) << 16;
    float f; __builtin_memcpy(&f, &i, 4); return f;
}
DEVINL unsigned short f2b(float f) {
    unsigned int i; __builtin_memcpy(&i, &f, 4);
    unsigned int r = (i + 0x7FFFu + ((i >> 16) & 1u)) >> 16;  // RTN-even
    return (unsigned short)r;
}

// ---------------------------------------------------------------------------
__global__ void zero_cnt_kernel(int* __restrict__ cnt) {
    if (threadIdx.x < 8) cnt[threadIdx.x] = 0;
}

// ---------------------------------------------------------------------------
// convT: src fp32 [batch][R][C] -> dst bf16 [batch][C][R]  (B-operand layout)
__global__ __launch_bounds__(256) void convT_kernel(
    const float* __restrict__ src, short* __restrict__ dst, int R, int C, int total)
{
    int idx = blockIdx.x * 256 + threadIdx.x;
    if (idx >= total) return;
    int rc = R * C;
    int bM = idx / rc;
    int rem = idx - bM * rc;
    int c = rem / R;
    int r = rem - c * R;
    dst[idx] = (short)f2b(src[(size_t)bM * rc + (size_t)r * C + c]);
}

// ---------------------------------------------------------------------------
// gate: double-precision logits (stable top-2 vs numpy ref)
__global__ __launch_bounds__(256) void gate_kernel(
    const float* __restrict__ x, const float* __restrict__ Wg, const float* __restrict__ bg,
    int* __restrict__ cnt, int* __restrict__ rlist, float* __restrict__ wlist)
{
    const int b = blockIdx.x;
    const int tid = threadIdx.x;
    const int e8 = tid & 7;
    const int seg = tid >> 3;
    const float* gi = x + (size_t)b * 8192;
    double p = 0.0;
    for (int ii = 0; ii < 256; ++ii) {
        int i = seg * 256 + ii;
        p += (double)gi[i] * (double)Wg[i * 8 + e8];
    }
    p += __shfl_xor(p, 8, 64);
    p += __shfl_xor(p, 16, 64);
    p += __shfl_xor(p, 32, 64);
    __shared__ double wred[4 * 8];
    const int lane = tid & 63, w = tid >> 6;
    if (lane < 8) wred[w * 8 + lane] = p;
    __syncthreads();
    if (tid == 0) {
        double lg[8];
        for (int e = 0; e < 8; ++e)
            lg[e] = wred[e] + wred[8 + e] + wred[16 + e] + wred[24 + e] + (double)bg[e];
        int i1 = 0;
        for (int e = 1; e < 8; ++e) if (lg[e] > lg[i1]) i1 = e;
        int i2 = (i1 == 0) ? 1 : 0;
        for (int e = 0; e < 8; ++e) if (e != i1 && lg[e] > lg[i2]) i2 = e;
        double ex = exp(lg[i2] - lg[i1]);
        float w1 = (float)(1.0 / (1.0 + ex));
        float w2 = (float)(ex / (1.0 + ex));
        int p1 = atomicAdd(&cnt[i1], 1);
        rlist[i1 * 512 + p1] = b; wlist[i1 * 512 + p1] = w1;
        int p2 = atomicAdd(&cnt[i2], 1);
        rlist[i2 * 512 + p2] = b; wlist[i2 * 512 + p2] = w2;
    }
}

// ---------------------------------------------------------------------------
// resproj: 2 batch rows per block, 256 blocks
__global__ __launch_bounds__(256) void resproj_kernel(
    const float* __restrict__ x, const float* __restrict__ Wr, const float* __restrict__ br,
    float* __restrict__ acc_out)
{
    const int b0 = blockIdx.x * 2;
    const int tid = threadIdx.x;
    const int d = tid & 63;
    const int part = tid >> 6;
    float acc0 = 0.f, acc1 = 0.f;
    for (int ii = 0; ii < 2048; ++ii) {
        int i = part * 2048 + ii;
        float wv = Wr[i * 64 + d];
        acc0 += x[(size_t)b0 * 8192 + i] * wv;
        acc1 += x[(size_t)(b0 + 1) * 8192 + i] * wv;
    }
    __shared__ float rr[4][2][64];
    rr[part][0][d] = acc0;
    rr[part][1][d] = acc1;
    __syncthreads();
    if (tid < 128) {
        int k = tid >> 6, dd = tid & 63;
        float v = rr[0][k][dd] + rr[1][k][dd] + rr[2][k][dd] + rr[3][k][dd];
        acc_out[(b0 + k) * 64 + dd] = 0.1f * (v + br[dd]);
    }
}

// ---------------------------------------------------------------------------
// expert kernel — 512 threads / 8 waves / M-split pairs.
// Wave w = (rh = w>>2, cg = w&3) owns output rows [rh*32, +32) and cols
// [cg*64, +64) of every GEMM -> 2 waves/SIMD.
// ROUND 6: the 126MB "spill" traffic of rounds 1-5 was rule-#20 scratch:
// the hp (head) loop lost its #pragma unroll in round 1, so
// avr[hp*4+rt*2+ct2] was runtime-indexed -> whole avr[8] array in scratch,
// stored in the attention loop + reloaded at writeback, every layer
// (~512B/thread ~ observed 126MB). VGPR counts of 112-128 were never a cap;
// avr simply wasn't in registers. Fix: #pragma unroll on hp -> all indices
// compile-time. Everything else identical to round 5.
// XCD pin: e = blockIdx&7 so each XCD's L2 holds one expert's weight image.
__global__ __launch_bounds__(512, 1) void expert_kernel(
    const float* __restrict__ x,
    const short* __restrict__ WinT, const float* __restrict__ bin_,
    const short* __restrict__ WqT,  const float* __restrict__ bq,
    const short* __restrict__ WkT,  const float* __restrict__ bk,
    const short* __restrict__ WvT,  const float* __restrict__ bv,
    const short* __restrict__ WoT,  const float* __restrict__ bo,
    const float* __restrict__ ln1g, const float* __restrict__ ln1b,
    const float* __restrict__ ln2g, const float* __restrict__ ln2b,
    const short* __restrict__ W1T,  const float* __restrict__ b1,
    const short* __restrict__ W2T,  const float* __restrict__ b2,
    const float* __restrict__ Wout, const float* __restrict__ bout,
    const int* __restrict__ cnt, const int* __restrict__ rlist,
    const float* __restrict__ wlist, float* __restrict__ acc_out)
{
    const int e = blockIdx.x & 7;          // XCD pin
    const int s = blockIdx.x >> 3;
    if (s >= cnt[e]) return;
    const int b   = rlist[e * 512 + s];
    const float wgt = wlist[e * 512 + s];
    const int tid = threadIdx.x;
    const int lane = tid & 63;
    const int wg  = __builtin_amdgcn_readfirstlane(tid >> 6);
    const int ln = lane & 15, quad = lane >> 4;
    const int cg = wg & 3;                 // col group: cols [cg*64, +64)
    const int rh = wg >> 2;                // row half:  rows [rh*32, +32)
    const int nb = cg * 64;
    const int r0 = rh * 32;

    // LDS: 33,792 + 96,256 + 2,048 + 2,048 = 134,144 B -> 1 block/CU (8 waves)
    __shared__ __align__(16) unsigned short hS[64 * 264];      // residual/av/LN out
    __shared__ __align__(16) unsigned short attnS[4 * 12032];  // per-pair attn | xS | tS
    __shared__ float redS[512];                                // LN cross-wave partials
    __shared__ float pooledS[512];                             // 2 row-half partials
    unsigned short* Qw  = attnS + cg * 12032;  // [64][40]
    unsigned short* Kw  = Qw + 2560;           // [64][40]
    unsigned short* VTw = Qw + 5120;           // [32][72]
    unsigned short* PSw = Qw + 7424;           // [64][72] (own buffer, no overlay)
    unsigned short* xS  = attnS;               // [64][136] (block-shared, P0/P1)

    // ---- P0: stage x[b] -> xS bf16 row-major ----
    {
        const float* xb = x + (size_t)b * 8192;
        #pragma unroll
        for (int i = 0; i < 16; ++i) {
            int id = tid + 512 * i;
            xS[(id >> 7) * 136 + (id & 127)] = f2b(xb[id]);
        }
    }
    __syncthreads();

    f32x4 hr[8];   // residual: wave's 32 rows x 64 cols, [rt*4+ct]

    // ---- P1: h0 = x @ Win + bin (K=128) ----
    {
        const short* BW = WinT + (size_t)e * 32768;
        const float* bp = bin_ + e * 256;
        #pragma unroll
        for (int ct = 0; ct < 4; ++ct) {
            bf16x8 Bf[4];
            #pragma unroll
            for (int kt = 0; kt < 4; ++kt)
                Bf[kt] = *(const bf16x8*)(BW + (size_t)(nb + ct * 16 + ln) * 128 + kt * 32 + quad * 8);
            const float bz = bp[nb + ct * 16 + ln];
            #pragma unroll
            for (int rt = 0; rt < 2; ++rt) {
                bf16x8 Af[4];
                #pragma unroll
                for (int kt = 0; kt < 4; ++kt)
                    Af[kt] = *(const bf16x8*)&xS[(r0 + rt * 16 + ln) * 136 + kt * 32 + quad * 8];
                f32x4 c = {bz, bz, bz, bz};
                #pragma unroll
                for (int kt = 0; kt < 4; ++kt) c = MFMA16(Af[kt], Bf[kt], c);
                hr[rt * 4 + ct] = c;
                #pragma unroll
                for (int i = 0; i < 4; ++i)
                    hS[(r0 + rt * 16 + quad * 4 + i) * 264 + nb + ct * 16 + ln] = f2b(c[i]);
            }
        }
    }
    __syncthreads();

    // LayerNorm over acc; cross-wave via redS; writes hr + hS.
    auto LN = [&](f32x4* a, const float* g, const float* bb) {
        #pragma unroll
        for (int rt = 0; rt < 2; ++rt)
            #pragma unroll
            for (int i = 0; i < 4; ++i) {
                float s1 = 0.f, s2 = 0.f;
                #pragma unroll
                for (int ct = 0; ct < 4; ++ct) { float v = a[rt * 4 + ct][i]; s1 += v; s2 += v * v; }
                s1 += __shfl_xor(s1, 1); s1 += __shfl_xor(s1, 2);
                s1 += __shfl_xor(s1, 4); s1 += __shfl_xor(s1, 8);
                s2 += __shfl_xor(s2, 1); s2 += __shfl_xor(s2, 2);
                s2 += __shfl_xor(s2, 4); s2 += __shfl_xor(s2, 8);
                if (ln == 0) {
                    int row = r0 + rt * 16 + quad * 4 + i;
                    redS[row * 8 + cg * 2] = s1;
                    redS[row * 8 + cg * 2 + 1] = s2;
                }
            }
        __syncthreads();
        float gv[4], bv2[4];
        #pragma unroll
        for (int ct = 0; ct < 4; ++ct) { gv[ct] = g[nb + ct * 16 + ln]; bv2[ct] = bb[nb + ct * 16 + ln]; }
        #pragma unroll
        for (int rt = 0; rt < 2; ++rt)
            #pragma unroll
            for (int i = 0; i < 4; ++i) {
                int row = r0 + rt * 16 + quad * 4 + i;
                float S1 = redS[row * 8 + 0] + redS[row * 8 + 2] + redS[row * 8 + 4] + redS[row * 8 + 6];
                float S2 = redS[row * 8 + 1] + redS[row * 8 + 3] + redS[row * 8 + 5] + redS[row * 8 + 7];
                float m_ = S1 * (1.f / 256.f);
                float rstd = rsqrtf(S2 * (1.f / 256.f) - m_ * m_ + 1e-5f);
                #pragma unroll
                for (int ct = 0; ct < 4; ++ct) {
                    float v = (a[rt * 4 + ct][i] - m_) * rstd * gv[ct] + bv2[ct];
                    hr[rt * 4 + ct][i] = v;
                    hS[row * 264 + nb + ct * 16 + ln] = f2b(v);
                }
            }
        __syncthreads();
    };

    for (int l = 0; l < 2; ++l) {
        const int el = e * 2 + l;
        const short* WqE = WqT + (size_t)el * 65536;
        const short* WkE = WkT + (size_t)el * 65536;
        const short* WvE = WvT + (size_t)el * 65536;
        const short* WoE = WoT + (size_t)el * 65536;
        const short* W1E = W1T + (size_t)el * 262144;
        const short* W2E = W2T + (size_t)el * 262144;
        const float* bq_p = bq + el * 256;
        const float* bk_p = bk + el * 256;
        const float* bv_p = bv + el * 256;
        const float* bo_p = bo + el * 256;

        f32x4 avr[8];   // both heads' av: [hp*4 + rt*2 + ct2] — hp unrolled => static idx

        // ---- QKV + attention: pair (rh=0,cg)+(rh=1,cg) shares slot cg ----
        #pragma unroll
        for (int hp = 0; hp < 2; ++hp) {
            const int hb = nb + hp * 32;   // head (2*cg+hp) col base

            // No A-hoisting: A-frags re-read from hS per ct2 (arch-pressure fix).
            auto qkv = [&](const short* WB, const float* bbp, unsigned short* dQK, int isV) {
                #pragma unroll
                for (int ct2 = 0; ct2 < 2; ++ct2) {
                    bf16x8 Bq[8];
                    #pragma unroll
                    for (int kt = 0; kt < 8; ++kt)
                        Bq[kt] = *(const bf16x8*)(WB + (size_t)(hb + ct2 * 16 + ln) * 256 + kt * 32 + quad * 8);
                    const float bz2 = bbp[hb + ct2 * 16 + ln];
                    #pragma unroll
                    for (int rt = 0; rt < 2; ++rt) {
                        bf16x8 Af[8];
                        #pragma unroll
                        for (int kt = 0; kt < 8; ++kt)
                            Af[kt] = *(const bf16x8*)&hS[(r0 + rt * 16 + ln) * 264 + kt * 32 + quad * 8];
                        f32x4 c = {bz2, bz2, bz2, bz2};
                        #pragma unroll
                        for (int kt = 0; kt < 8; ++kt) c = MFMA16(Af[kt], Bq[kt], c);
                        if (!isV) {
                            #pragma unroll
                            for (int i = 0; i < 4; ++i)
                                dQK[(r0 + rt * 16 + quad * 4 + i) * 40 + ct2 * 16 + ln] = f2b(c[i]);
                        } else {
                            #pragma unroll
                            for (int i = 0; i < 4; ++i)
                                VTw[(ct2 * 16 + ln) * 72 + r0 + rt * 16 + quad * 4 + i] = f2b(c[i]);
                        }
                    }
                }
            };
            qkv(WqE, bq_p, Qw, 0);
            qkv(WkE, bk_p, Kw, 0);
            qkv(WvE, bv_p, nullptr, 1);
            __syncthreads();   // pair's K/VT rows complete (also: hS reads done)

            // --- S = Q K^T (M=32 own rows, N=64, K=32) ---
            f32x4 sc[8];
            {
                bf16x8 Bk[4];
                #pragma unroll
                for (int ck = 0; ck < 4; ++ck)
                    Bk[ck] = *(const bf16x8*)&Kw[(ck * 16 + ln) * 40 + quad * 8];
                #pragma unroll
                for (int rt = 0; rt < 2; ++rt) {
                    bf16x8 Aq = *(const bf16x8*)&Qw[(r0 + rt * 16 + ln) * 40 + quad * 8];
                    #pragma unroll
                    for (int ck = 0; ck < 4; ++ck) {
                        f32x4 z = {0.f, 0.f, 0.f, 0.f};
                        sc[rt * 4 + ck] = MFMA16(Aq, Bk[ck], z);
                    }
                }
            }
            // --- softmax per row (in-wave, 16-lane groups) ---
            const float sscale = 0.17677669529663687f;  // 1/sqrt(32)
            #pragma unroll
            for (int t = 0; t < 8; ++t)
                #pragma unroll
                for (int i = 0; i < 4; ++i) sc[t][i] *= sscale;
            #pragma unroll
            for (int rt = 0; rt < 2; ++rt)
                #pragma unroll
                for (int i = 0; i < 4; ++i) {
                    float m_ = fmaxf(fmaxf(sc[rt * 4 + 0][i], sc[rt * 4 + 1][i]),
                                     fmaxf(sc[rt * 4 + 2][i], sc[rt * 4 + 3][i]));
                    m_ = fmaxf(m_, __shfl_xor(m_, 1));
                    m_ = fmaxf(m_, __shfl_xor(m_, 2));
                    m_ = fmaxf(m_, __shfl_xor(m_, 4));
                    m_ = fmaxf(m_, __shfl_xor(m_, 8));
                    float s_ = 0.f;
                    #pragma unroll
                    for (int ck = 0; ck < 4; ++ck) {
                        sc[rt * 4 + ck][i] = __expf(sc[rt * 4 + ck][i] - m_);
                        s_ += sc[rt * 4 + ck][i];
                    }
                    s_ += __shfl_xor(s_, 1); s_ += __shfl_xor(s_, 2);
                    s_ += __shfl_xor(s_, 4); s_ += __shfl_xor(s_, 8);
                    float inv = 1.f / s_;
                    int row = r0 + rt * 16 + quad * 4 + i;
                    #pragma unroll
                    for (int ck = 0; ck < 4; ++ck)
                        PSw[row * 72 + ck * 16 + ln] = f2b(sc[rt * 4 + ck][i] * inv);
                }

            // --- av = P @ V (M=32 own rows, N=32, K=64); PS rows are own-wave ---
            {
                #pragma unroll
                for (int ct2 = 0; ct2 < 2; ++ct2) {
                    bf16x8 Bv[2];
                    #pragma unroll
                    for (int kt2 = 0; kt2 < 2; ++kt2)
                        Bv[kt2] = *(const bf16x8*)&VTw[(ct2 * 16 + ln) * 72 + kt2 * 32 + quad * 8];
                    #pragma unroll
                    for (int rt = 0; rt < 2; ++rt) {
                        bf16x8 Ap[2];
                        #pragma unroll
                        for (int kt2 = 0; kt2 < 2; ++kt2)
                            Ap[kt2] = *(const bf16x8*)&PSw[(r0 + rt * 16 + ln) * 72 + kt2 * 32 + quad * 8];
                        f32x4 c = {0.f, 0.f, 0.f, 0.f};
                        #pragma unroll
                        for (int kt2 = 0; kt2 < 2; ++kt2) c = MFMA16(Ap[kt2], Bv[kt2], c);
                        avr[hp * 4 + rt * 2 + ct2] = c;
                    }
                }
            }
            if (hp == 0) __syncthreads();  // partner done reading Kw/VTw before hp=1 overwrites
        }

        // write av (wave's 32 rows x 64 cols) -> hS; hS(h) reads all done at last barrier
        #pragma unroll
        for (int hp = 0; hp < 2; ++hp)
            #pragma unroll
            for (int rt = 0; rt < 2; ++rt)
                #pragma unroll
                for (int ct2 = 0; ct2 < 2; ++ct2)
                    #pragma unroll
                    for (int i = 0; i < 4; ++i)
                        hS[(r0 + rt * 16 + quad * 4 + i) * 264 + nb + hp * 32 + ct2 * 16 + ln]
                            = f2b(avr[hp * 4 + rt * 2 + ct2][i]);
        __syncthreads();

        // ---- O-proj: oacc = h + bo + av @ Wo (K=256); no hoisting ----
        f32x4 oacc[8];
        #pragma unroll
        for (int rt = 0; rt < 2; ++rt)
            #pragma unroll
            for (int ct = 0; ct < 4; ++ct) {
                float bz = bo_p[nb + ct * 16 + ln];
                f32x4 t = hr[rt * 4 + ct];
                t[0] += bz; t[1] += bz; t[2] += bz; t[3] += bz;
                oacc[rt * 4 + ct] = t;
            }
        #pragma unroll
        for (int ct = 0; ct < 4; ++ct) {
            bf16x8 Bo[8];
            #pragma unroll
            for (int kt = 0; kt < 8; ++kt)
                Bo[kt] = *(const bf16x8*)(WoE + (size_t)(nb + ct * 16 + ln) * 256 + kt * 32 + quad * 8);
            #pragma unroll
            for (int rt = 0; rt < 2; ++rt) {
                bf16x8 Ao[8];
                #pragma unroll
                for (int kt = 0; kt < 8; ++kt)
                    Ao[kt] = *(const bf16x8*)&hS[(r0 + rt * 16 + ln) * 264 + kt * 32 + quad * 8];
                #pragma unroll
                for (int kt = 0; kt < 8; ++kt)
                    oacc[rt * 4 + ct] = MFMA16(Ao[kt], Bo[kt], oacc[rt * 4 + ct]);
            }
        }

        // ---- LN1 -> hr, hS ----
        LN(oacc, ln1g + el * 256, ln1b + el * 256);

        // ---- FF: 8 chunks of 128 FF cols, tS double-buffered (1 barrier/chunk) ----
        f32x4 facc[8];
        {
            const float* b2_p = b2 + el * 256;
            #pragma unroll
            for (int rt = 0; rt < 2; ++rt)
                #pragma unroll
                for (int ct = 0; ct < 4; ++ct) {
                    float bz = b2_p[nb + ct * 16 + ln];
                    f32x4 t = hr[rt * 4 + ct];
                    t[0] += bz; t[1] += bz; t[2] += bz; t[3] += bz;
                    facc[rt * 4 + ct] = t;
                }
        }
        const float* b1_p = b1 + el * 1024;
        for (int ch = 0; ch < 8; ++ch) {
            const int fb = ch * 128 + cg * 32;       // wave's 32 FF cols this chunk
            unsigned short* tC = attnS + (ch & 1) * 8704;   // [64][136] dbuf
            #pragma unroll
            for (int ct2 = 0; ct2 < 2; ++ct2) {
                bf16x8 B1c[8];
                #pragma unroll
                for (int kt = 0; kt < 8; ++kt)
                    B1c[kt] = *(const bf16x8*)(W1E + (size_t)(fb + ct2 * 16 + ln) * 256 + kt * 32 + quad * 8);
                const float bz2 = b1_p[fb + ct2 * 16 + ln];
                #pragma unroll
                for (int rt = 0; rt < 2; ++rt) {
                    bf16x8 Af[8];
                    #pragma unroll
                    for (int kt = 0; kt < 8; ++kt)
                        Af[kt] = *(const bf16x8*)&hS[(r0 + rt * 16 + ln) * 264 + kt * 32 + quad * 8];
                    f32x4 c = {bz2, bz2, bz2, bz2};
                    #pragma unroll
                    for (int kt = 0; kt < 8; ++kt) c = MFMA16(Af[kt], B1c[kt], c);
                    #pragma unroll
                    for (int i = 0; i < 4; ++i)
                        tC[(r0 + rt * 16 + quad * 4 + i) * 136 + cg * 32 + ct2 * 16 + ln]
                            = f2b(fmaxf(c[i], 0.f));
                }
            }
            __syncthreads();
            // W2 partial: K=128 (B loaded once per ct; A re-read per ct from tC)
            #pragma unroll
            for (int ct = 0; ct < 4; ++ct) {
                bf16x8 B2c[4];
                #pragma unroll
                for (int kt2 = 0; kt2 < 4; ++kt2)
                    B2c[kt2] = *(const bf16x8*)(W2E + (size_t)(nb + ct * 16 + ln) * 1024 + ch * 128 + kt2 * 32 + quad * 8);
                #pragma unroll
                for (int rt = 0; rt < 2; ++rt) {
                    bf16x8 At[4];
                    #pragma unroll
                    for (int kt2 = 0; kt2 < 4; ++kt2)
                        At[kt2] = *(const bf16x8*)&tC[(r0 + rt * 16 + ln) * 136 + kt2 * 32 + quad * 8];
                    #pragma unroll
                    for (int kt2 = 0; kt2 < 4; ++kt2)
                        facc[rt * 4 + ct] = MFMA16(At[kt2], B2c[kt2], facc[rt * 4 + ct]);
                }
            }
            // no barrier: next W1 writes the other tS buffer
        }

        // ---- LN2 -> hr, hS ----
        LN(facc, ln2g + el * 256, ln2b + el * 256);
    }

    // ---- pooling + Wout + weighted combine ----
    {
        #pragma unroll
        for (int ct = 0; ct < 4; ++ct) {
            float s_ = 0.f;
            #pragma unroll
            for (int rt = 0; rt < 2; ++rt)
                #pragma unroll
                for (int i = 0; i < 4; ++i) s_ += hr[rt * 4 + ct][i];
            s_ += __shfl_xor(s_, 16);
            s_ += __shfl_xor(s_, 32);
            if (quad == 0) pooledS[rh * 256 + nb + ct * 16 + ln] = s_;
        }
        __syncthreads();
        if (tid < 64) {
            const float* Wout_p = Wout + (size_t)e * (256 * 64);
            float o = bout[e * 64 + tid];
            for (int c = 0; c < 256; ++c)
                o += (pooledS[c] + pooledS[256 + c]) * (1.f / 64.f) * Wout_p[c * 64 + tid];
            atomicAdd(&acc_out[b * 64 + tid], wgt * o);
        }
    }
}

// ---------------------------------------------------------------------------
__global__ __launch_bounds__(64) void final_ln_kernel(
    const float* __restrict__ acc_out, const float* __restrict__ on_g,
    const float* __restrict__ on_b, float* __restrict__ out)
{
    const int b = blockIdx.x;
    const int d = threadIdx.x;
    float v = acc_out[b * 64 + d];
    float s1 = v, s2 = v * v;
    #pragma unroll
    for (int st = 1; st < 64; st <<= 1) {
        s1 += __shfl_xor(s1, st, 64);
        s2 += __shfl_xor(s2, st, 64);
    }
    float m   = s1 * (1.f / 64.f);
    float var = s2 * (1.f / 64.f) - m * m;
    float rstd = rsqrtf(var + 1e-5f);
    out[b * 64 + d] = (v - m) * rstd * on_g[d] + on_b[d];
}

// ---------------------------------------------------------------------------
extern "C" void kernel_launch(void* const* d_in, const int* in_sizes, int n_in,
                              void* d_out, int out_size, void* d_ws, size_t ws_size,
                              hipStream_t stream)
{
    (void)in_sizes; (void)n_in; (void)out_size; (void)ws_size;
    const float* x    = (const float*)d_in[0];
    const float* Win  = (const float*)d_in[1];
    const float* bin_ = (const float*)d_in[2];
    const float* Wq   = (const float*)d_in[3];
    const float* bq   = (const float*)d_in[4];
    const float* Wk   = (const float*)d_in[5];
    const float* bk   = (const float*)d_in[6];
    const float* Wv   = (const float*)d_in[7];
    const float* bv   = (const float*)d_in[8];
    const float* Wo   = (const float*)d_in[9];
    const float* bo   = (const float*)d_in[10];
    const float* ln1g = (const float*)d_in[11];
    const float* ln1b = (const float*)d_in[12];
    const float* ln2g = (const float*)d_in[13];
    const float* ln2b = (const float*)d_in[14];
    const float* W1   = (const float*)d_in[15];
    const float* b1   = (const float*)d_in[16];
    const float* W2   = (const float*)d_in[17];
    const float* b2   = (const float*)d_in[18];
    const float* Wout = (const float*)d_in[19];
    const float* bout = (const float*)d_in[20];
    const float* Wg   = (const float*)d_in[21];
    const float* bg   = (const float*)d_in[22];
    const float* Wr   = (const float*)d_in[23];
    const float* br   = (const float*)d_in[24];
    const float* on_g = (const float*)d_in[25];
    const float* on_b = (const float*)d_in[26];
    float* out = (float*)d_out;

    // workspace carve-up
    char* ws = (char*)d_ws;
    float* acc_out = (float*)ws;                         // 131,072 B
    int*   cnt     = (int*)(ws + 131072);
    int*   rlist   = (int*)(ws + 131200);                // 16,384 B
    float* wlist   = (float*)(ws + 147584);              // 16,384 B
    short* WinT    = (short*)(ws + 164096);              //   524,288 B
    short* WqT     = (short*)(ws + 688384);              // 2,097,152 B
    short* WkT     = (short*)(ws + 2785536);
    short* WvT     = (short*)(ws + 4882688);
    short* WoT     = (short*)(ws + 6979840);
    short* W1T     = (short*)(ws + 9076992);             // 8,388,608 B
    short* W2T     = (short*)(ws + 17465600);            // 8,388,608 B

    // weight transposition fp32 [R][C] -> bf16 [C][R]
    convT_kernel<<<1024, 256, 0, stream>>>(Win, WinT, 128, 256, 262144);
    convT_kernel<<<4096, 256, 0, stream>>>(Wq, WqT, 256, 256, 1048576);
    convT_kernel<<<4096, 256, 0, stream>>>(Wk, WkT, 256, 256, 1048576);
    convT_kernel<<<4096, 256, 0, stream>>>(Wv, WvT, 256, 256, 1048576);
    convT_kernel<<<4096, 256, 0, stream>>>(Wo, WoT, 256, 256, 1048576);
    convT_kernel<<<16384, 256, 0, stream>>>(W1, W1T, 256, 1024, 4194304);
    convT_kernel<<<16384, 256, 0, stream>>>(W2, W2T, 1024, 256, 4194304);

    zero_cnt_kernel<<<1, 64, 0, stream>>>(cnt);
    gate_kernel<<<512, 256, 0, stream>>>(x, Wg, bg, cnt, rlist, wlist);
    resproj_kernel<<<256, 256, 0, stream>>>(x, Wr, br, acc_out);
    expert_kernel<<<4096, 512, 0, stream>>>(x,
        WinT, bin_, WqT, bq, WkT, bk, WvT, bv, WoT, bo,
        ln1g, ln1b, ln2g, ln2b, W1T, b1, W2T, b2, Wout, bout,
        cnt, rlist, wlist, acc_out);
    final_ln_kernel<<<512, 64, 0, stream>>>(acc_out, on_g, on_b, out);
}

// Round 8
// 1128.755 us; speedup vs baseline: 1.3463x; 1.2941x over previous
//
#include <hip/hip_runtime.h>
#include <hip/hip_bf16.h>

// B=512, S=64, IN=128, DM=256, H=8, HD=32, L=2, FF=1024, DO=64, E=8, K=2, GI=8192

typedef __attribute__((ext_vector_type(8))) short bf16x8;
typedef __attribute__((ext_vector_type(4))) float f32x4;

#define DEVINL __device__ __forceinline__
#define MFMA16(a, b, c) __builtin_amdgcn_mfma_f32_16x16x32_bf16((a), (b), (c), 0, 0, 0)

DEVINL float b2f(unsigned short u) {
    unsigned int i = ((unsigned int)u) << 16;
    float f; __builtin_memcpy(&f, &i, 4); return f;
}
DEVINL unsigned short f2b(float f) {
    unsigned int i; __builtin_memcpy(&i, &f, 4);
    unsigned int r = (i + 0x7FFFu + ((i >> 16) & 1u)) >> 16;  // RTN-even
    return (unsigned short)r;
}

// ---------------------------------------------------------------------------
__global__ void zero_cnt_kernel(int* __restrict__ cnt) {
    if (threadIdx.x < 8) cnt[threadIdx.x] = 0;
}

// ---------------------------------------------------------------------------
// convT: src fp32 [batch][R][C] -> dst bf16 [batch][C][R]  (B-operand layout)
__global__ __launch_bounds__(256) void convT_kernel(
    const float* __restrict__ src, short* __restrict__ dst, int R, int C, int total)
{
    int idx = blockIdx.x * 256 + threadIdx.x;
    if (idx >= total) return;
    int rc = R * C;
    int bM = idx / rc;
    int rem = idx - bM * rc;
    int c = rem / R;
    int r = rem - c * R;
    dst[idx] = (short)f2b(src[(size_t)bM * rc + (size_t)r * C + c]);
}

// ---------------------------------------------------------------------------
// gate: double-precision logits (stable top-2 vs numpy ref)
__global__ __launch_bounds__(256) void gate_kernel(
    const float* __restrict__ x, const float* __restrict__ Wg, const float* __restrict__ bg,
    int* __restrict__ cnt, int* __restrict__ rlist, float* __restrict__ wlist)
{
    const int b = blockIdx.x;
    const int tid = threadIdx.x;
    const int e8 = tid & 7;
    const int seg = tid >> 3;
    const float* gi = x + (size_t)b * 8192;
    double p = 0.0;
    for (int ii = 0; ii < 256; ++ii) {
        int i = seg * 256 + ii;
        p += (double)gi[i] * (double)Wg[i * 8 + e8];
    }
    p += __shfl_xor(p, 8, 64);
    p += __shfl_xor(p, 16, 64);
    p += __shfl_xor(p, 32, 64);
    __shared__ double wred[4 * 8];
    const int lane = tid & 63, w = tid >> 6;
    if (lane < 8) wred[w * 8 + lane] = p;
    __syncthreads();
    if (tid == 0) {
        double lg[8];
        for (int e = 0; e < 8; ++e)
            lg[e] = wred[e] + wred[8 + e] + wred[16 + e] + wred[24 + e] + (double)bg[e];
        int i1 = 0;
        for (int e = 1; e < 8; ++e) if (lg[e] > lg[i1]) i1 = e;
        int i2 = (i1 == 0) ? 1 : 0;
        for (int e = 0; e < 8; ++e) if (e != i1 && lg[e] > lg[i2]) i2 = e;
        double ex = exp(lg[i2] - lg[i1]);
        float w1 = (float)(1.0 / (1.0 + ex));
        float w2 = (float)(ex / (1.0 + ex));
        int p1 = atomicAdd(&cnt[i1], 1);
        rlist[i1 * 512 + p1] = b; wlist[i1 * 512 + p1] = w1;
        int p2 = atomicAdd(&cnt[i2], 1);
        rlist[i2 * 512 + p2] = b; wlist[i2 * 512 + p2] = w2;
    }
}

// ---------------------------------------------------------------------------
// resproj: 2 batch rows per block, 256 blocks
__global__ __launch_bounds__(256) void resproj_kernel(
    const float* __restrict__ x, const float* __restrict__ Wr, const float* __restrict__ br,
    float* __restrict__ acc_out)
{
    const int b0 = blockIdx.x * 2;
    const int tid = threadIdx.x;
    const int d = tid & 63;
    const int part = tid >> 6;
    float acc0 = 0.f, acc1 = 0.f;
    for (int ii = 0; ii < 2048; ++ii) {
        int i = part * 2048 + ii;
        float wv = Wr[i * 64 + d];
        acc0 += x[(size_t)b0 * 8192 + i] * wv;
        acc1 += x[(size_t)(b0 + 1) * 8192 + i] * wv;
    }
    __shared__ float rr[4][2][64];
    rr[part][0][d] = acc0;
    rr[part][1][d] = acc1;
    __syncthreads();
    if (tid < 128) {
        int k = tid >> 6, dd = tid & 63;
        float v = rr[0][k][dd] + rr[1][k][dd] + rr[2][k][dd] + rr[3][k][dd];
        acc_out[(b0 + k) * 64 + dd] = 0.1f * (v + br[dd]);
    }
}

// ---------------------------------------------------------------------------
// expert kernel — ROUND 7 resubmit (round-7 bench was an infra failure):
// revert to the 4-wave round-0 structure (937 µs verified) and get
// 2 waves/SIMD via 2 INDEPENDENT blocks/CU instead of the failed 8-wave
// lockstep pair (round 6: 1151 µs, spill-free).
// LDS diet 92,160 -> 73,728 B (< 80 KB -> 2 blocks/CU):
//   attention reordered per head: Q -> K -> QK^T (scores to regs) ->
//   V overlays dead Q buffer; softmax'd P written in TWO 32-col passes
//   into dead K buffer ([64][36]), PV split into two K-halves between
//   passes. All wave-private, in-order LDS, no new barriers.
//   Per-wave attn: 6912 -> 4608 shorts.
// __launch_bounds__(256, 2) enforces <=256 regs (2 waves/SIMD).
// Chunked B-loads (8 frags) keep peak live ~244 regs (sc[16] is live
// through the V GEMM in the new order).
// FF keeps the tS double-buffer (1 barrier/chunk; 2x8704 <= 18432 sh).
// XCD pin: e = blockIdx&7 so each XCD's L2 holds one expert's weight image.
__global__ __launch_bounds__(256, 2) void expert_kernel(
    const float* __restrict__ x,
    const short* __restrict__ WinT, const float* __restrict__ bin_,
    const short* __restrict__ WqT,  const float* __restrict__ bq,
    const short* __restrict__ WkT,  const float* __restrict__ bk,
    const short* __restrict__ WvT,  const float* __restrict__ bv,
    const short* __restrict__ WoT,  const float* __restrict__ bo,
    const float* __restrict__ ln1g, const float* __restrict__ ln1b,
    const float* __restrict__ ln2g, const float* __restrict__ ln2b,
    const short* __restrict__ W1T,  const float* __restrict__ b1,
    const short* __restrict__ W2T,  const float* __restrict__ b2,
    const float* __restrict__ Wout, const float* __restrict__ bout,
    const int* __restrict__ cnt, const int* __restrict__ rlist,
    const float* __restrict__ wlist, float* __restrict__ acc_out)
{
    const int e = blockIdx.x & 7;          // XCD pin
    const int s = blockIdx.x >> 3;
    if (s >= cnt[e]) return;
    const int b   = rlist[e * 512 + s];
    const float wgt = wlist[e * 512 + s];
    const int tid = threadIdx.x;
    const int lane = tid & 63;
    const int wg  = __builtin_amdgcn_readfirstlane(tid >> 6);
    const int ln = lane & 15, quad = lane >> 4;
    const int nb = wg * 64;                // wave's output-column base

    // LDS: 33,792 + 36,864 + 2,048 + 1,024 = 73,728 B -> 2 blocks/CU
    __shared__ __align__(16) unsigned short hS[64 * 264];     // residual/av/LN out
    __shared__ __align__(16) unsigned short attnS[4 * 4608];  // per-wave attn | xS | tS
    __shared__ float redS[512];                               // LN cross-wave partials
    __shared__ float pooledS[256];
    unsigned short* Qw  = attnS + wg * 4608;  // [64][36] Q
    unsigned short* Kw  = Qw + 2304;          // [64][36] K
    unsigned short* VTw = Qw;                 // [32][72] V^T (overlays dead Q)
    unsigned short* PSw = Kw;                 // [64][36] P half (overlays dead K)
    unsigned short* xS  = attnS;              // [64][136] (block-shared, P0/P1)

    // ---- P0: stage x[b] -> xS bf16 row-major ----
    {
        const float* xb = x + (size_t)b * 8192;
        #pragma unroll
        for (int i = 0; i < 32; ++i) {
            int id = tid + 256 * i;
            xS[(id >> 7) * 136 + (id & 127)] = f2b(xb[id]);
        }
    }
    __syncthreads();

    f32x4 hr[16];   // residual: wave's 64 rows x 64 cols, [rt*4+ct]

    // ---- P1: h0 = x @ Win + bin (K=128) ----
    {
        const short* BW = WinT + (size_t)e * 32768;
        const float* bp = bin_ + e * 256;
        #pragma unroll
        for (int ct = 0; ct < 4; ++ct) {
            bf16x8 Bf[4];
            #pragma unroll
            for (int kt = 0; kt < 4; ++kt)
                Bf[kt] = *(const bf16x8*)(BW + (size_t)(nb + ct * 16 + ln) * 128 + kt * 32 + quad * 8);
            const float bz = bp[nb + ct * 16 + ln];
            #pragma unroll
            for (int rt = 0; rt < 4; ++rt) {
                bf16x8 Af[4];
                #pragma unroll
                for (int kt = 0; kt < 4; ++kt)
                    Af[kt] = *(const bf16x8*)&xS[(rt * 16 + ln) * 136 + kt * 32 + quad * 8];
                f32x4 c = {bz, bz, bz, bz};
                #pragma unroll
                for (int kt = 0; kt < 4; ++kt) c = MFMA16(Af[kt], Bf[kt], c);
                hr[rt * 4 + ct] = c;
                #pragma unroll
                for (int i = 0; i < 4; ++i)
                    hS[(rt * 16 + quad * 4 + i) * 264 + nb + ct * 16 + ln] = f2b(c[i]);
            }
        }
    }
    __syncthreads();

    // LayerNorm over acc (C-layout); cross-wave via redS; writes hr + hS.
    auto LN = [&](f32x4* a, const float* g, const float* bb) {
        #pragma unroll
        for (int rt = 0; rt < 4; ++rt)
            #pragma unroll
            for (int i = 0; i < 4; ++i) {
                float s1 = 0.f, s2 = 0.f;
                #pragma unroll
                for (int ct = 0; ct < 4; ++ct) { float v = a[rt * 4 + ct][i]; s1 += v; s2 += v * v; }
                s1 += __shfl_xor(s1, 1); s1 += __shfl_xor(s1, 2);
                s1 += __shfl_xor(s1, 4); s1 += __shfl_xor(s1, 8);
                s2 += __shfl_xor(s2, 1); s2 += __shfl_xor(s2, 2);
                s2 += __shfl_xor(s2, 4); s2 += __shfl_xor(s2, 8);
                if (ln == 0) {
                    int row = rt * 16 + quad * 4 + i;
                    redS[row * 8 + wg * 2] = s1;
                    redS[row * 8 + wg * 2 + 1] = s2;
                }
            }
        __syncthreads();
        float gv[4], bv2[4];
        #pragma unroll
        for (int ct = 0; ct < 4; ++ct) { gv[ct] = g[nb + ct * 16 + ln]; bv2[ct] = bb[nb + ct * 16 + ln]; }
        #pragma unroll
        for (int rt = 0; rt < 4; ++rt)
            #pragma unroll
            for (int i = 0; i < 4; ++i) {
                int row = rt * 16 + quad * 4 + i;
                float S1 = redS[row * 8 + 0] + redS[row * 8 + 2] + redS[row * 8 + 4] + redS[row * 8 + 6];
                float S2 = redS[row * 8 + 1] + redS[row * 8 + 3] + redS[row * 8 + 5] + redS[row * 8 + 7];
                float m_ = S1 * (1.f / 256.f);
                float rstd = rsqrtf(S2 * (1.f / 256.f) - m_ * m_ + 1e-5f);
                #pragma unroll
                for (int ct = 0; ct < 4; ++ct) {
                    float v = (a[rt * 4 + ct][i] - m_) * rstd * gv[ct] + bv2[ct];
                    hr[rt * 4 + ct][i] = v;
                    hS[row * 264 + nb + ct * 16 + ln] = f2b(v);
                }
            }
        __syncthreads();
    };

    for (int l = 0; l < 2; ++l) {
        const int el = e * 2 + l;
        const short* WqE = WqT + (size_t)el * 65536;
        const short* WkE = WkT + (size_t)el * 65536;
        const short* WvE = WvT + (size_t)el * 65536;
        const short* WoE = WoT + (size_t)el * 65536;
        const short* W1E = W1T + (size_t)el * 262144;
        const short* W2E = W2T + (size_t)el * 262144;
        const float* bq_p = bq + el * 256;
        const float* bk_p = bk + el * 256;
        const float* bv_p = bv + el * 256;
        const float* bo_p = bo + el * 256;

        f32x4 avr[16];   // both heads' av: [hp*8 + rt*2 + ct2]

        // ---- QKV + attention, fully wave-private (no barriers inside) ----
        #pragma unroll
        for (int hp = 0; hp < 2; ++hp) {
            const int hb = nb + hp * 32;   // head (2wg+hp) col base

            // GEMM h @ W (M=64, N=32, K=256) -> row-major dst [64][36]
            auto qkvQK = [&](const short* WB, const float* bbp, unsigned short* dst) {
                #pragma unroll
                for (int ct2 = 0; ct2 < 2; ++ct2) {
                    bf16x8 Bq[8];
                    #pragma unroll
                    for (int kt = 0; kt < 8; ++kt)
                        Bq[kt] = *(const bf16x8*)(WB + (size_t)(hb + ct2 * 16 + ln) * 256 + kt * 32 + quad * 8);
                    const float bz2 = bbp[hb + ct2 * 16 + ln];
                    #pragma unroll
                    for (int rt = 0; rt < 4; ++rt) {
                        bf16x8 Af[8];
                        #pragma unroll
                        for (int kt = 0; kt < 8; ++kt)
                            Af[kt] = *(const bf16x8*)&hS[(rt * 16 + ln) * 264 + kt * 32 + quad * 8];
                        f32x4 c = {bz2, bz2, bz2, bz2};
                        #pragma unroll
                        for (int kt = 0; kt < 8; ++kt) c = MFMA16(Af[kt], Bq[kt], c);
                        #pragma unroll
                        for (int i = 0; i < 4; ++i)
                            dst[(rt * 16 + quad * 4 + i) * 36 + ct2 * 16 + ln] = f2b(c[i]);
                    }
                }
            };
            qkvQK(WqE, bq_p, Qw);
            qkvQK(WkE, bk_p, Kw);

            // --- S = Q K^T (M=64, N=64, K=32); Q,K LDS dead afterwards ---
            f32x4 sc[16];
            {
                bf16x8 Bk[4];
                #pragma unroll
                for (int ck = 0; ck < 4; ++ck)
                    Bk[ck] = *(const bf16x8*)&Kw[(ck * 16 + ln) * 36 + quad * 8];
                #pragma unroll
                for (int rt = 0; rt < 4; ++rt) {
                    bf16x8 Aq = *(const bf16x8*)&Qw[(rt * 16 + ln) * 36 + quad * 8];
                    #pragma unroll
                    for (int ck = 0; ck < 4; ++ck) {
                        f32x4 z = {0.f, 0.f, 0.f, 0.f};
                        sc[rt * 4 + ck] = MFMA16(Aq, Bk[ck], z);
                    }
                }
            }

            // --- V GEMM -> VTw [32][72] (overlays dead Q region) ---
            {
                #pragma unroll
                for (int ct2 = 0; ct2 < 2; ++ct2) {
                    bf16x8 Bq[8];
                    #pragma unroll
                    for (int kt = 0; kt < 8; ++kt)
                        Bq[kt] = *(const bf16x8*)(WvE + (size_t)(hb + ct2 * 16 + ln) * 256 + kt * 32 + quad * 8);
                    const float bz2 = bv_p[hb + ct2 * 16 + ln];
                    #pragma unroll
                    for (int rt = 0; rt < 4; ++rt) {
                        bf16x8 Af[8];
                        #pragma unroll
                        for (int kt = 0; kt < 8; ++kt)
                            Af[kt] = *(const bf16x8*)&hS[(rt * 16 + ln) * 264 + kt * 32 + quad * 8];
                        f32x4 c = {bz2, bz2, bz2, bz2};
                        #pragma unroll
                        for (int kt = 0; kt < 8; ++kt) c = MFMA16(Af[kt], Bq[kt], c);
                        #pragma unroll
                        for (int i = 0; i < 4; ++i)
                            VTw[(ct2 * 16 + ln) * 72 + rt * 16 + quad * 4 + i] = f2b(c[i]);
                    }
                }
            }

            // --- softmax, fully normalized in registers ---
            const float sscale = 0.17677669529663687f;  // 1/sqrt(32)
            #pragma unroll
            for (int t = 0; t < 16; ++t)
                #pragma unroll
                for (int i = 0; i < 4; ++i) sc[t][i] *= sscale;
            #pragma unroll
            for (int rt = 0; rt < 4; ++rt)
                #pragma unroll
                for (int i = 0; i < 4; ++i) {
                    float m_ = fmaxf(fmaxf(sc[rt * 4 + 0][i], sc[rt * 4 + 1][i]),
                                     fmaxf(sc[rt * 4 + 2][i], sc[rt * 4 + 3][i]));
                    m_ = fmaxf(m_, __shfl_xor(m_, 1));
                    m_ = fmaxf(m_, __shfl_xor(m_, 2));
                    m_ = fmaxf(m_, __shfl_xor(m_, 4));
                    m_ = fmaxf(m_, __shfl_xor(m_, 8));
                    float s_ = 0.f;
                    #pragma unroll
                    for (int ck = 0; ck < 4; ++ck) {
                        sc[rt * 4 + ck][i] = __expf(sc[rt * 4 + ck][i] - m_);
                        s_ += sc[rt * 4 + ck][i];
                    }
                    s_ += __shfl_xor(s_, 1); s_ += __shfl_xor(s_, 2);
                    s_ += __shfl_xor(s_, 4); s_ += __shfl_xor(s_, 8);
                    float inv = 1.f / s_;
                    #pragma unroll
                    for (int ck = 0; ck < 4; ++ck) sc[rt * 4 + ck][i] *= inv;
                }

            // --- two-pass P write (PSw [64][36] overlays dead K) + PV halves ---
            // pass 0: P cols 0..31
            #pragma unroll
            for (int rt = 0; rt < 4; ++rt)
                #pragma unroll
                for (int i = 0; i < 4; ++i)
                    #pragma unroll
                    for (int ck = 0; ck < 2; ++ck)
                        PSw[(rt * 16 + quad * 4 + i) * 36 + ck * 16 + ln] = f2b(sc[rt * 4 + ck][i]);
            {
                bf16x8 Bv0[2];
                #pragma unroll
                for (int ct2 = 0; ct2 < 2; ++ct2)
                    Bv0[ct2] = *(const bf16x8*)&VTw[(ct2 * 16 + ln) * 72 + quad * 8];
                #pragma unroll
                for (int rt = 0; rt < 4; ++rt) {
                    bf16x8 Ap = *(const bf16x8*)&PSw[(rt * 16 + ln) * 36 + quad * 8];
                    #pragma unroll
                    for (int ct2 = 0; ct2 < 2; ++ct2) {
                        f32x4 z = {0.f, 0.f, 0.f, 0.f};
                        avr[hp * 8 + rt * 2 + ct2] = MFMA16(Ap, Bv0[ct2], z);
                    }
                }
            }
            // pass 1: P cols 32..63 (overwrite; in-order LDS, same-wave alias kept)
            #pragma unroll
            for (int rt = 0; rt < 4; ++rt)
                #pragma unroll
                for (int i = 0; i < 4; ++i)
                    #pragma unroll
                    for (int ck = 2; ck < 4; ++ck)
                        PSw[(rt * 16 + quad * 4 + i) * 36 + (ck - 2) * 16 + ln] = f2b(sc[rt * 4 + ck][i]);
            {
                bf16x8 Bv1[2];
                #pragma unroll
                for (int ct2 = 0; ct2 < 2; ++ct2)
                    Bv1[ct2] = *(const bf16x8*)&VTw[(ct2 * 16 + ln) * 72 + 32 + quad * 8];
                #pragma unroll
                for (int rt = 0; rt < 4; ++rt) {
                    bf16x8 Ap = *(const bf16x8*)&PSw[(rt * 16 + ln) * 36 + quad * 8];
                    #pragma unroll
                    for (int ct2 = 0; ct2 < 2; ++ct2)
                        avr[hp * 8 + rt * 2 + ct2] = MFMA16(Ap, Bv1[ct2], avr[hp * 8 + rt * 2 + ct2]);
                }
            }
        }

        __syncthreads();   // all waves done reading hS(h)
        // write av (wave's exact 64-col strip) -> hS
        #pragma unroll
        for (int hp = 0; hp < 2; ++hp)
            #pragma unroll
            for (int rt = 0; rt < 4; ++rt)
                #pragma unroll
                for (int ct2 = 0; ct2 < 2; ++ct2)
                    #pragma unroll
                    for (int i = 0; i < 4; ++i)
                        hS[(rt * 16 + quad * 4 + i) * 264 + nb + hp * 32 + ct2 * 16 + ln]
                            = f2b(avr[hp * 8 + rt * 2 + ct2][i]);
        __syncthreads();

        // ---- O-proj: oacc = h + bo + av @ Wo (K=256) ----
        f32x4 oacc[16];
        #pragma unroll
        for (int rt = 0; rt < 4; ++rt)
            #pragma unroll
            for (int ct = 0; ct < 4; ++ct) {
                float bz = bo_p[nb + ct * 16 + ln];
                f32x4 t = hr[rt * 4 + ct];
                t[0] += bz; t[1] += bz; t[2] += bz; t[3] += bz;
                oacc[rt * 4 + ct] = t;
            }
        #pragma unroll
        for (int ct = 0; ct < 4; ++ct) {
            bf16x8 Bo[8];
            #pragma unroll
            for (int kt = 0; kt < 8; ++kt)
                Bo[kt] = *(const bf16x8*)(WoE + (size_t)(nb + ct * 16 + ln) * 256 + kt * 32 + quad * 8);
            #pragma unroll
            for (int rt = 0; rt < 4; ++rt) {
                bf16x8 Ao[8];
                #pragma unroll
                for (int kt = 0; kt < 8; ++kt)
                    Ao[kt] = *(const bf16x8*)&hS[(rt * 16 + ln) * 264 + kt * 32 + quad * 8];
                #pragma unroll
                for (int kt = 0; kt < 8; ++kt)
                    oacc[rt * 4 + ct] = MFMA16(Ao[kt], Bo[kt], oacc[rt * 4 + ct]);
            }
        }

        // ---- LN1 -> hr, hS ----
        LN(oacc, ln1g + el * 256, ln1b + el * 256);

        // ---- FF: 8 chunks of 128 FF cols, tS double-buffered (1 barrier/chunk) ----
        f32x4 facc[16];
        {
            const float* b2_p = b2 + el * 256;
            #pragma unroll
            for (int rt = 0; rt < 4; ++rt)
                #pragma unroll
                for (int ct = 0; ct < 4; ++ct) {
                    float bz = b2_p[nb + ct * 16 + ln];
                    f32x4 t = hr[rt * 4 + ct];
                    t[0] += bz; t[1] += bz; t[2] += bz; t[3] += bz;
                    facc[rt * 4 + ct] = t;
                }
        }
        const float* b1_p = b1 + el * 1024;
        for (int ch = 0; ch < 8; ++ch) {
            const int fb = ch * 128 + wg * 32;       // wave's 32 FF cols this chunk
            unsigned short* tC = attnS + (ch & 1) * 8704;   // [64][136] dbuf
            #pragma unroll
            for (int ct2 = 0; ct2 < 2; ++ct2) {
                bf16x8 B1c[8];
                #pragma unroll
                for (int kt = 0; kt < 8; ++kt)
                    B1c[kt] = *(const bf16x8*)(W1E + (size_t)(fb + ct2 * 16 + ln) * 256 + kt * 32 + quad * 8);
                const float bz2 = b1_p[fb + ct2 * 16 + ln];
                #pragma unroll
                for (int rt = 0; rt < 4; ++rt) {
                    bf16x8 Af[8];
                    #pragma unroll
                    for (int kt = 0; kt < 8; ++kt)
                        Af[kt] = *(const bf16x8*)&hS[(rt * 16 + ln) * 264 + kt * 32 + quad * 8];
                    f32x4 c = {bz2, bz2, bz2, bz2};
                    #pragma unroll
                    for (int kt = 0; kt < 8; ++kt) c = MFMA16(Af[kt], B1c[kt], c);
                    #pragma unroll
                    for (int i = 0; i < 4; ++i)
                        tC[(rt * 16 + quad * 4 + i) * 136 + wg * 32 + ct2 * 16 + ln]
                            = f2b(fmaxf(c[i], 0.f));
                }
            }
            __syncthreads();
            // W2 partial: K=128
            #pragma unroll
            for (int ct = 0; ct < 4; ++ct) {
                bf16x8 B2c[4];
                #pragma unroll
                for (int kt2 = 0; kt2 < 4; ++kt2)
                    B2c[kt2] = *(const bf16x8*)(W2E + (size_t)(nb + ct * 16 + ln) * 1024 + ch * 128 + kt2 * 32 + quad * 8);
                #pragma unroll
                for (int rt = 0; rt < 4; ++rt) {
                    bf16x8 At[4];
                    #pragma unroll
                    for (int kt2 = 0; kt2 < 4; ++kt2)
                        At[kt2] = *(const bf16x8*)&tC[(rt * 16 + ln) * 136 + kt2 * 32 + quad * 8];
                    #pragma unroll
                    for (int kt2 = 0; kt2 < 4; ++kt2)
                        facc[rt * 4 + ct] = MFMA16(At[kt2], B2c[kt2], facc[rt * 4 + ct]);
                }
            }
            // no barrier: next W1 writes the other tS buffer
        }

        // ---- LN2 -> hr, hS ----
        LN(facc, ln2g + el * 256, ln2b + el * 256);
    }

    // ---- pooling + Wout + weighted combine ----
    {
        #pragma unroll
        for (int ct = 0; ct < 4; ++ct) {
            float s_ = 0.f;
            #pragma unroll
            for (int rt = 0; rt < 4; ++rt)
                #pragma unroll
                for (int i = 0; i < 4; ++i) s_ += hr[rt * 4 + ct][i];
            s_ += __shfl_xor(s_, 16);
            s_ += __shfl_xor(s_, 32);
            if (quad == 0) pooledS[nb + ct * 16 + ln] = s_ * (1.f / 64.f);
        }
        __syncthreads();
        if (tid < 64) {
            const float* Wout_p = Wout + (size_t)e * (256 * 64);
            float o = bout[e * 64 + tid];
            for (int c = 0; c < 256; ++c) o += pooledS[c] * Wout_p[c * 64 + tid];
            atomicAdd(&acc_out[b * 64 + tid], wgt * o);
        }
    }
}

// ---------------------------------------------------------------------------
__global__ __launch_bounds__(64) void final_ln_kernel(
    const float* __restrict__ acc_out, const float* __restrict__ on_g,
    const float* __restrict__ on_b, float* __restrict__ out)
{
    const int b = blockIdx.x;
    const int d = threadIdx.x;
    float v = acc_out[b * 64 + d];
    float s1 = v, s2 = v * v;
    #pragma unroll
    for (int st = 1; st < 64; st <<= 1) {
        s1 += __shfl_xor(s1, st, 64);
        s2 += __shfl_xor(s2, st, 64);
    }
    float m   = s1 * (1.f / 64.f);
    float var = s2 * (1.f / 64.f) - m * m;
    float rstd = rsqrtf(var + 1e-5f);
    out[b * 64 + d] = (v - m) * rstd * on_g[d] + on_b[d];
}

// ---------------------------------------------------------------------------
extern "C" void kernel_launch(void* const* d_in, const int* in_sizes, int n_in,
                              void* d_out, int out_size, void* d_ws, size_t ws_size,
                              hipStream_t stream)
{
    (void)in_sizes; (void)n_in; (void)out_size; (void)ws_size;
    const float* x    = (const float*)d_in[0];
    const float* Win  = (const float*)d_in[1];
    const float* bin_ = (const float*)d_in[2];
    const float* Wq   = (const float*)d_in[3];
    const float* bq   = (const float*)d_in[4];
    const float* Wk   = (const float*)d_in[5];
    const float* bk   = (const float*)d_in[6];
    const float* Wv   = (const float*)d_in[7];
    const float* bv   = (const float*)d_in[8];
    const float* Wo   = (const float*)d_in[9];
    const float* bo   = (const float*)d_in[10];
    const float* ln1g = (const float*)d_in[11];
    const float* ln1b = (const float*)d_in[12];
    const float* ln2g = (const float*)d_in[13];
    const float* ln2b = (const float*)d_in[14];
    const float* W1   = (const float*)d_in[15];
    const float* b1   = (const float*)d_in[16];
    const float* W2   = (const float*)d_in[17];
    const float* b2   = (const float*)d_in[18];
    const float* Wout = (const float*)d_in[19];
    const float* bout = (const float*)d_in[20];
    const float* Wg   = (const float*)d_in[21];
    const float* bg   = (const float*)d_in[22];
    const float* Wr   = (const float*)d_in[23];
    const float* br   = (const float*)d_in[24];
    const float* on_g = (const float*)d_in[25];
    const float* on_b = (const float*)d_in[26];
    float* out = (float*)d_out;

    // workspace carve-up
    char* ws = (char*)d_ws;
    float* acc_out = (float*)ws;                         // 131,072 B
    int*   cnt     = (int*)(ws + 131072);
    int*   rlist   = (int*)(ws + 131200);                // 16,384 B
    float* wlist   = (float*)(ws + 147584);              // 16,384 B
    short* WinT    = (short*)(ws + 164096);              //   524,288 B
    short* WqT     = (short*)(ws + 688384);              // 2,097,152 B
    short* WkT     = (short*)(ws + 2785536);
    short* WvT     = (short*)(ws + 4882688);
    short* WoT     = (short*)(ws + 6979840);
    short* W1T     = (short*)(ws + 9076992);             // 8,388,608 B
    short* W2T     = (short*)(ws + 17465600);            // 8,388,608 B

    // weight transposition fp32 [R][C] -> bf16 [C][R]
    convT_kernel<<<1024, 256, 0, stream>>>(Win, WinT, 128, 256, 262144);
    convT_kernel<<<4096, 256, 0, stream>>>(Wq, WqT, 256, 256, 1048576);
    convT_kernel<<<4096, 256, 0, stream>>>(Wk, WkT, 256, 256, 1048576);
    convT_kernel<<<4096, 256, 0, stream>>>(Wv, WvT, 256, 256, 1048576);
    convT_kernel<<<4096, 256, 0, stream>>>(Wo, WoT, 256, 256, 1048576);
    convT_kernel<<<16384, 256, 0, stream>>>(W1, W1T, 256, 1024, 4194304);
    convT_kernel<<<16384, 256, 0, stream>>>(W2, W2T, 1024, 256, 4194304);

    zero_cnt_kernel<<<1, 64, 0, stream>>>(cnt);
    gate_kernel<<<512, 256, 0, stream>>>(x, Wg, bg, cnt, rlist, wlist);
    resproj_kernel<<<256, 256, 0, stream>>>(x, Wr, br, acc_out);
    expert_kernel<<<4096, 256, 0, stream>>>(x,
        WinT, bin_, WqT, bq, WkT, bk, WvT, bv, WoT, bo,
        ln1g, ln1b, ln2g, ln2b, W1T, b1, W2T, b2, Wout, bout,
        cnt, rlist, wlist, acc_out);
    final_ln_kernel<<<512, 64, 0, stream>>>(acc_out, on_g, on_b, out);
}

// Round 9
// 1020.284 us; speedup vs baseline: 1.4894x; 1.1063x over previous
//
#include <hip/hip_runtime.h>
#include <hip/hip_bf16.h>

// B=512, S=64, IN=128, DM=256, H=8, HD=32, L=2, FF=1024, DO=64, E=8, K=2, GI=8192

typedef __attribute__((ext_vector_type(8))) short bf16x8;
typedef __attribute__((ext_vector_type(4))) float f32x4;

#define DEVINL __device__ __forceinline__
#define MFMA16(a, b, c) __builtin_amdgcn_mfma_f32_16x16x32_bf16((a), (b), (c), 0, 0, 0)

DEVINL float b2f(unsigned short u) {
    unsigned int i = ((unsigned int)u) << 16;
    float f; __builtin_memcpy(&f, &i, 4); return f;
}
DEVINL unsigned short f2b(float f) {
    unsigned int i; __builtin_memcpy(&i, &f, 4);
    unsigned int r = (i + 0x7FFFu + ((i >> 16) & 1u)) >> 16;  // RTN-even
    return (unsigned short)r;
}

// ---------------------------------------------------------------------------
__global__ void zero_cnt_kernel(int* __restrict__ cnt) {
    if (threadIdx.x < 8) cnt[threadIdx.x] = 0;
}

// ---------------------------------------------------------------------------
// convT: src fp32 [batch][R][C] -> dst bf16 [batch][C][R]  (B-operand layout)
__global__ __launch_bounds__(256) void convT_kernel(
    const float* __restrict__ src, short* __restrict__ dst, int R, int C, int total)
{
    int idx = blockIdx.x * 256 + threadIdx.x;
    if (idx >= total) return;
    int rc = R * C;
    int bM = idx / rc;
    int rem = idx - bM * rc;
    int c = rem / R;
    int r = rem - c * R;
    dst[idx] = (short)f2b(src[(size_t)bM * rc + (size_t)r * C + c]);
}

// ---------------------------------------------------------------------------
// gate: double-precision logits (stable top-2 vs numpy ref)
__global__ __launch_bounds__(256) void gate_kernel(
    const float* __restrict__ x, const float* __restrict__ Wg, const float* __restrict__ bg,
    int* __restrict__ cnt, int* __restrict__ rlist, float* __restrict__ wlist)
{
    const int b = blockIdx.x;
    const int tid = threadIdx.x;
    const int e8 = tid & 7;
    const int seg = tid >> 3;
    const float* gi = x + (size_t)b * 8192;
    double p = 0.0;
    for (int ii = 0; ii < 256; ++ii) {
        int i = seg * 256 + ii;
        p += (double)gi[i] * (double)Wg[i * 8 + e8];
    }
    p += __shfl_xor(p, 8, 64);
    p += __shfl_xor(p, 16, 64);
    p += __shfl_xor(p, 32, 64);
    __shared__ double wred[4 * 8];
    const int lane = tid & 63, w = tid >> 6;
    if (lane < 8) wred[w * 8 + lane] = p;
    __syncthreads();
    if (tid == 0) {
        double lg[8];
        for (int e = 0; e < 8; ++e)
            lg[e] = wred[e] + wred[8 + e] + wred[16 + e] + wred[24 + e] + (double)bg[e];
        int i1 = 0;
        for (int e = 1; e < 8; ++e) if (lg[e] > lg[i1]) i1 = e;
        int i2 = (i1 == 0) ? 1 : 0;
        for (int e = 0; e < 8; ++e) if (e != i1 && lg[e] > lg[i2]) i2 = e;
        double ex = exp(lg[i2] - lg[i1]);
        float w1 = (float)(1.0 / (1.0 + ex));
        float w2 = (float)(ex / (1.0 + ex));
        int p1 = atomicAdd(&cnt[i1], 1);
        rlist[i1 * 512 + p1] = b; wlist[i1 * 512 + p1] = w1;
        int p2 = atomicAdd(&cnt[i2], 1);
        rlist[i2 * 512 + p2] = b; wlist[i2 * 512 + p2] = w2;
    }
}

// ---------------------------------------------------------------------------
// resproj: 2 batch rows per block, 256 blocks
__global__ __launch_bounds__(256) void resproj_kernel(
    const float* __restrict__ x, const float* __restrict__ Wr, const float* __restrict__ br,
    float* __restrict__ acc_out)
{
    const int b0 = blockIdx.x * 2;
    const int tid = threadIdx.x;
    const int d = tid & 63;
    const int part = tid >> 6;
    float acc0 = 0.f, acc1 = 0.f;
    for (int ii = 0; ii < 2048; ++ii) {
        int i = part * 2048 + ii;
        float wv = Wr[i * 64 + d];
        acc0 += x[(size_t)b0 * 8192 + i] * wv;
        acc1 += x[(size_t)(b0 + 1) * 8192 + i] * wv;
    }
    __shared__ float rr[4][2][64];
    rr[part][0][d] = acc0;
    rr[part][1][d] = acc1;
    __syncthreads();
    if (tid < 128) {
        int k = tid >> 6, dd = tid & 63;
        float v = rr[0][k][dd] + rr[1][k][dd] + rr[2][k][dd] + rr[3][k][dd];
        acc_out[(b0 + k) * 64 + dd] = 0.1f * (v + br[dd]);
    }
}

// ---------------------------------------------------------------------------
// expert kernel — ROUND 9: round-8 got 2 blocks/CU (937->803 µs) but its
// attention reorder left sc[16] (64 regs) live across the V GEMM -> demand
// ~290 > the (256,2) cap -> 298MB spill traffic. Fix: restore sc-free V GEMM
// (V first, like round 0) while KEEPING the 2-block LDS diet by STREAMING K
// in 16-row chunks:
//   per head: V GEMM -> VTw[32][72] (own buf, sc not yet live)
//             Q GEMM -> Qw[64][36]
//             for ck<4: K-chunk GEMM (16 h-rows, Wk B-frags hoisted once)
//                       -> Kpart[16][36]; QK^T partial -> sc[rt*4+ck]
//             softmax; P two-pass over dead Q; PV halves.
// Per-wave LDS: 2304(VT)+2304(Q)+576(Kpart) = 5184 sh; block total
// 33,792 + 41,472 + 2,048 + 1,024 = 78,336 B < 80KB -> 2 blocks/CU.
// Peak regs ~ hr(64)+sc(64)+avr(64)+arch(~40) ~= 232 <= 256 -> no spill.
// XCD pin: e = blockIdx&7 so each XCD's L2 holds one expert's weight image.
__global__ __launch_bounds__(256, 2) void expert_kernel(
    const float* __restrict__ x,
    const short* __restrict__ WinT, const float* __restrict__ bin_,
    const short* __restrict__ WqT,  const float* __restrict__ bq,
    const short* __restrict__ WkT,  const float* __restrict__ bk,
    const short* __restrict__ WvT,  const float* __restrict__ bv,
    const short* __restrict__ WoT,  const float* __restrict__ bo,
    const float* __restrict__ ln1g, const float* __restrict__ ln1b,
    const float* __restrict__ ln2g, const float* __restrict__ ln2b,
    const short* __restrict__ W1T,  const float* __restrict__ b1,
    const short* __restrict__ W2T,  const float* __restrict__ b2,
    const float* __restrict__ Wout, const float* __restrict__ bout,
    const int* __restrict__ cnt, const int* __restrict__ rlist,
    const float* __restrict__ wlist, float* __restrict__ acc_out)
{
    const int e = blockIdx.x & 7;          // XCD pin
    const int s = blockIdx.x >> 3;
    if (s >= cnt[e]) return;
    const int b   = rlist[e * 512 + s];
    const float wgt = wlist[e * 512 + s];
    const int tid = threadIdx.x;
    const int lane = tid & 63;
    const int wg  = __builtin_amdgcn_readfirstlane(tid >> 6);
    const int ln = lane & 15, quad = lane >> 4;
    const int nb = wg * 64;                // wave's output-column base

    // LDS: 33,792 + 41,472 + 2,048 + 1,024 = 78,336 B -> 2 blocks/CU
    __shared__ __align__(16) unsigned short hS[64 * 264];     // residual/av/LN out
    __shared__ __align__(16) unsigned short attnS[4 * 5184];  // per-wave attn | xS | tS
    __shared__ float redS[512];                               // LN cross-wave partials
    __shared__ float pooledS[256];
    unsigned short* VTw   = attnS + wg * 5184;  // [32][72] V^T
    unsigned short* Qw    = VTw + 2304;         // [64][36] Q
    unsigned short* Kpart = VTw + 4608;         // [16][36] K chunk
    unsigned short* PSw   = Qw;                 // [64][36] P half (overlays dead Q)
    unsigned short* xS    = attnS;              // [64][136] (block-shared, P0/P1)

    // ---- P0: stage x[b] -> xS bf16 row-major ----
    {
        const float* xb = x + (size_t)b * 8192;
        #pragma unroll
        for (int i = 0; i < 32; ++i) {
            int id = tid + 256 * i;
            xS[(id >> 7) * 136 + (id & 127)] = f2b(xb[id]);
        }
    }
    __syncthreads();

    f32x4 hr[16];   // residual: wave's 64 rows x 64 cols, [rt*4+ct]

    // ---- P1: h0 = x @ Win + bin (K=128) ----
    {
        const short* BW = WinT + (size_t)e * 32768;
        const float* bp = bin_ + e * 256;
        #pragma unroll
        for (int ct = 0; ct < 4; ++ct) {
            bf16x8 Bf[4];
            #pragma unroll
            for (int kt = 0; kt < 4; ++kt)
                Bf[kt] = *(const bf16x8*)(BW + (size_t)(nb + ct * 16 + ln) * 128 + kt * 32 + quad * 8);
            const float bz = bp[nb + ct * 16 + ln];
            #pragma unroll
            for (int rt = 0; rt < 4; ++rt) {
                bf16x8 Af[4];
                #pragma unroll
                for (int kt = 0; kt < 4; ++kt)
                    Af[kt] = *(const bf16x8*)&xS[(rt * 16 + ln) * 136 + kt * 32 + quad * 8];
                f32x4 c = {bz, bz, bz, bz};
                #pragma unroll
                for (int kt = 0; kt < 4; ++kt) c = MFMA16(Af[kt], Bf[kt], c);
                hr[rt * 4 + ct] = c;
                #pragma unroll
                for (int i = 0; i < 4; ++i)
                    hS[(rt * 16 + quad * 4 + i) * 264 + nb + ct * 16 + ln] = f2b(c[i]);
            }
        }
    }
    __syncthreads();

    // LayerNorm over acc (C-layout); cross-wave via redS; writes hr + hS.
    auto LN = [&](f32x4* a, const float* g, const float* bb) {
        #pragma unroll
        for (int rt = 0; rt < 4; ++rt)
            #pragma unroll
            for (int i = 0; i < 4; ++i) {
                float s1 = 0.f, s2 = 0.f;
                #pragma unroll
                for (int ct = 0; ct < 4; ++ct) { float v = a[rt * 4 + ct][i]; s1 += v; s2 += v * v; }
                s1 += __shfl_xor(s1, 1); s1 += __shfl_xor(s1, 2);
                s1 += __shfl_xor(s1, 4); s1 += __shfl_xor(s1, 8);
                s2 += __shfl_xor(s2, 1); s2 += __shfl_xor(s2, 2);
                s2 += __shfl_xor(s2, 4); s2 += __shfl_xor(s2, 8);
                if (ln == 0) {
                    int row = rt * 16 + quad * 4 + i;
                    redS[row * 8 + wg * 2] = s1;
                    redS[row * 8 + wg * 2 + 1] = s2;
                }
            }
        __syncthreads();
        float gv[4], bv2[4];
        #pragma unroll
        for (int ct = 0; ct < 4; ++ct) { gv[ct] = g[nb + ct * 16 + ln]; bv2[ct] = bb[nb + ct * 16 + ln]; }
        #pragma unroll
        for (int rt = 0; rt < 4; ++rt)
            #pragma unroll
            for (int i = 0; i < 4; ++i) {
                int row = rt * 16 + quad * 4 + i;
                float S1 = redS[row * 8 + 0] + redS[row * 8 + 2] + redS[row * 8 + 4] + redS[row * 8 + 6];
                float S2 = redS[row * 8 + 1] + redS[row * 8 + 3] + redS[row * 8 + 5] + redS[row * 8 + 7];
                float m_ = S1 * (1.f / 256.f);
                float rstd = rsqrtf(S2 * (1.f / 256.f) - m_ * m_ + 1e-5f);
                #pragma unroll
                for (int ct = 0; ct < 4; ++ct) {
                    float v = (a[rt * 4 + ct][i] - m_) * rstd * gv[ct] + bv2[ct];
                    hr[rt * 4 + ct][i] = v;
                    hS[row * 264 + nb + ct * 16 + ln] = f2b(v);
                }
            }
        __syncthreads();
    };

    for (int l = 0; l < 2; ++l) {
        const int el = e * 2 + l;
        const short* WqE = WqT + (size_t)el * 65536;
        const short* WkE = WkT + (size_t)el * 65536;
        const short* WvE = WvT + (size_t)el * 65536;
        const short* WoE = WoT + (size_t)el * 65536;
        const short* W1E = W1T + (size_t)el * 262144;
        const short* W2E = W2T + (size_t)el * 262144;
        const float* bq_p = bq + el * 256;
        const float* bk_p = bk + el * 256;
        const float* bv_p = bv + el * 256;
        const float* bo_p = bo + el * 256;

        f32x4 avr[16];   // both heads' av: [hp*8 + rt*2 + ct2]

        // ---- QKV + attention, fully wave-private (no barriers inside) ----
        #pragma unroll
        for (int hp = 0; hp < 2; ++hp) {
            const int hb = nb + hp * 32;   // head (2wg+hp) col base

            // --- V GEMM -> VTw [32][72] (sc not live here) ---
            #pragma unroll
            for (int ct2 = 0; ct2 < 2; ++ct2) {
                bf16x8 Bq[8];
                #pragma unroll
                for (int kt = 0; kt < 8; ++kt)
                    Bq[kt] = *(const bf16x8*)(WvE + (size_t)(hb + ct2 * 16 + ln) * 256 + kt * 32 + quad * 8);
                const float bz2 = bv_p[hb + ct2 * 16 + ln];
                #pragma unroll
                for (int rt = 0; rt < 4; ++rt) {
                    bf16x8 Af[8];
                    #pragma unroll
                    for (int kt = 0; kt < 8; ++kt)
                        Af[kt] = *(const bf16x8*)&hS[(rt * 16 + ln) * 264 + kt * 32 + quad * 8];
                    f32x4 c = {bz2, bz2, bz2, bz2};
                    #pragma unroll
                    for (int kt = 0; kt < 8; ++kt) c = MFMA16(Af[kt], Bq[kt], c);
                    #pragma unroll
                    for (int i = 0; i < 4; ++i)
                        VTw[(ct2 * 16 + ln) * 72 + rt * 16 + quad * 4 + i] = f2b(c[i]);
                }
            }

            // --- Q GEMM -> Qw [64][36] ---
            #pragma unroll
            for (int ct2 = 0; ct2 < 2; ++ct2) {
                bf16x8 Bq[8];
                #pragma unroll
                for (int kt = 0; kt < 8; ++kt)
                    Bq[kt] = *(const bf16x8*)(WqE + (size_t)(hb + ct2 * 16 + ln) * 256 + kt * 32 + quad * 8);
                const float bz2 = bq_p[hb + ct2 * 16 + ln];
                #pragma unroll
                for (int rt = 0; rt < 4; ++rt) {
                    bf16x8 Af[8];
                    #pragma unroll
                    for (int kt = 0; kt < 8; ++kt)
                        Af[kt] = *(const bf16x8*)&hS[(rt * 16 + ln) * 264 + kt * 32 + quad * 8];
                    f32x4 c = {bz2, bz2, bz2, bz2};
                    #pragma unroll
                    for (int kt = 0; kt < 8; ++kt) c = MFMA16(Af[kt], Bq[kt], c);
                    #pragma unroll
                    for (int i = 0; i < 4; ++i)
                        Qw[(rt * 16 + quad * 4 + i) * 36 + ct2 * 16 + ln] = f2b(c[i]);
                }
            }

            // --- K streamed in 16-row chunks: K-chunk GEMM + QK^T partial ---
            // Wk B-frags are ck-invariant: hoist once per head.
            f32x4 sc[16];
            {
                bf16x8 WkB[16];
                float bkz[2];
                #pragma unroll
                for (int ct2 = 0; ct2 < 2; ++ct2) {
                    bkz[ct2] = bk_p[hb + ct2 * 16 + ln];
                    #pragma unroll
                    for (int kt = 0; kt < 8; ++kt)
                        WkB[ct2 * 8 + kt] = *(const bf16x8*)(WkE + (size_t)(hb + ct2 * 16 + ln) * 256 + kt * 32 + quad * 8);
                }
                #pragma unroll
                for (int ck = 0; ck < 4; ++ck) {
                    // K rows ck*16..+15  (= h rows; A-frag rows ck*16+ln)
                    bf16x8 Af[8];
                    #pragma unroll
                    for (int kt = 0; kt < 8; ++kt)
                        Af[kt] = *(const bf16x8*)&hS[(ck * 16 + ln) * 264 + kt * 32 + quad * 8];
                    #pragma unroll
                    for (int ct2 = 0; ct2 < 2; ++ct2) {
                        f32x4 c = {bkz[ct2], bkz[ct2], bkz[ct2], bkz[ct2]};
                        #pragma unroll
                        for (int kt = 0; kt < 8; ++kt) c = MFMA16(Af[kt], WkB[ct2 * 8 + kt], c);
                        #pragma unroll
                        for (int i = 0; i < 4; ++i)
                            Kpart[(quad * 4 + i) * 36 + ct2 * 16 + ln] = f2b(c[i]);
                    }
                    // QK^T partial: S cols ck*16..+15 (Kpart row ln, k=quad*8)
                    bf16x8 Bk = *(const bf16x8*)&Kpart[ln * 36 + quad * 8];
                    #pragma unroll
                    for (int rt = 0; rt < 4; ++rt) {
                        bf16x8 Aq = *(const bf16x8*)&Qw[(rt * 16 + ln) * 36 + quad * 8];
                        f32x4 z = {0.f, 0.f, 0.f, 0.f};
                        sc[rt * 4 + ck] = MFMA16(Aq, Bk, z);
                    }
                }
            }

            // --- softmax, fully normalized in registers ---
            const float sscale = 0.17677669529663687f;  // 1/sqrt(32)
            #pragma unroll
            for (int t = 0; t < 16; ++t)
                #pragma unroll
                for (int i = 0; i < 4; ++i) sc[t][i] *= sscale;
            #pragma unroll
            for (int rt = 0; rt < 4; ++rt)
                #pragma unroll
                for (int i = 0; i < 4; ++i) {
                    float m_ = fmaxf(fmaxf(sc[rt * 4 + 0][i], sc[rt * 4 + 1][i]),
                                     fmaxf(sc[rt * 4 + 2][i], sc[rt * 4 + 3][i]));
                    m_ = fmaxf(m_, __shfl_xor(m_, 1));
                    m_ = fmaxf(m_, __shfl_xor(m_, 2));
                    m_ = fmaxf(m_, __shfl_xor(m_, 4));
                    m_ = fmaxf(m_, __shfl_xor(m_, 8));
                    float s_ = 0.f;
                    #pragma unroll
                    for (int ck = 0; ck < 4; ++ck) {
                        sc[rt * 4 + ck][i] = __expf(sc[rt * 4 + ck][i] - m_);
                        s_ += sc[rt * 4 + ck][i];
                    }
                    s_ += __shfl_xor(s_, 1); s_ += __shfl_xor(s_, 2);
                    s_ += __shfl_xor(s_, 4); s_ += __shfl_xor(s_, 8);
                    float inv = 1.f / s_;
                    #pragma unroll
                    for (int ck = 0; ck < 4; ++ck) sc[rt * 4 + ck][i] *= inv;
                }

            // --- two-pass P write (PSw [64][36] overlays dead Q) + PV halves ---
            // pass 0: P cols 0..31
            #pragma unroll
            for (int rt = 0; rt < 4; ++rt)
                #pragma unroll
                for (int i = 0; i < 4; ++i)
                    #pragma unroll
                    for (int ck = 0; ck < 2; ++ck)
                        PSw[(rt * 16 + quad * 4 + i) * 36 + ck * 16 + ln] = f2b(sc[rt * 4 + ck][i]);
            {
                bf16x8 Bv0[2];
                #pragma unroll
                for (int ct2 = 0; ct2 < 2; ++ct2)
                    Bv0[ct2] = *(const bf16x8*)&VTw[(ct2 * 16 + ln) * 72 + quad * 8];
                #pragma unroll
                for (int rt = 0; rt < 4; ++rt) {
                    bf16x8 Ap = *(const bf16x8*)&PSw[(rt * 16 + ln) * 36 + quad * 8];
                    #pragma unroll
                    for (int ct2 = 0; ct2 < 2; ++ct2) {
                        f32x4 z = {0.f, 0.f, 0.f, 0.f};
                        avr[hp * 8 + rt * 2 + ct2] = MFMA16(Ap, Bv0[ct2], z);
                    }
                }
            }
            // pass 1: P cols 32..63 (overwrite; in-order LDS, same-wave alias kept)
            #pragma unroll
            for (int rt = 0; rt < 4; ++rt)
                #pragma unroll
                for (int i = 0; i < 4; ++i)
                    #pragma unroll
                    for (int ck = 2; ck < 4; ++ck)
                        PSw[(rt * 16 + quad * 4 + i) * 36 + (ck - 2) * 16 + ln] = f2b(sc[rt * 4 + ck][i]);
            {
                bf16x8 Bv1[2];
                #pragma unroll
                for (int ct2 = 0; ct2 < 2; ++ct2)
                    Bv1[ct2] = *(const bf16x8*)&VTw[(ct2 * 16 + ln) * 72 + 32 + quad * 8];
                #pragma unroll
                for (int rt = 0; rt < 4; ++rt) {
                    bf16x8 Ap = *(const bf16x8*)&PSw[(rt * 16 + ln) * 36 + quad * 8];
                    #pragma unroll
                    for (int ct2 = 0; ct2 < 2; ++ct2)
                        avr[hp * 8 + rt * 2 + ct2] = MFMA16(Ap, Bv1[ct2], avr[hp * 8 + rt * 2 + ct2]);
                }
            }
        }

        __syncthreads();   // all waves done reading hS(h)
        // write av (wave's exact 64-col strip) -> hS
        #pragma unroll
        for (int hp = 0; hp < 2; ++hp)
            #pragma unroll
            for (int rt = 0; rt < 4; ++rt)
                #pragma unroll
                for (int ct2 = 0; ct2 < 2; ++ct2)
                    #pragma unroll
                    for (int i = 0; i < 4; ++i)
                        hS[(rt * 16 + quad * 4 + i) * 264 + nb + hp * 32 + ct2 * 16 + ln]
                            = f2b(avr[hp * 8 + rt * 2 + ct2][i]);
        __syncthreads();

        // ---- O-proj: oacc = h + bo + av @ Wo (K=256) ----
        f32x4 oacc[16];
        #pragma unroll
        for (int rt = 0; rt < 4; ++rt)
            #pragma unroll
            for (int ct = 0; ct < 4; ++ct) {
                float bz = bo_p[nb + ct * 16 + ln];
                f32x4 t = hr[rt * 4 + ct];
                t[0] += bz; t[1] += bz; t[2] += bz; t[3] += bz;
                oacc[rt * 4 + ct] = t;
            }
        #pragma unroll
        for (int ct = 0; ct < 4; ++ct) {
            bf16x8 Bo[8];
            #pragma unroll
            for (int kt = 0; kt < 8; ++kt)
                Bo[kt] = *(const bf16x8*)(WoE + (size_t)(nb + ct * 16 + ln) * 256 + kt * 32 + quad * 8);
            #pragma unroll
            for (int rt = 0; rt < 4; ++rt) {
                bf16x8 Ao[8];
                #pragma unroll
                for (int kt = 0; kt < 8; ++kt)
                    Ao[kt] = *(const bf16x8*)&hS[(rt * 16 + ln) * 264 + kt * 32 + quad * 8];
                #pragma unroll
                for (int kt = 0; kt < 8; ++kt)
                    oacc[rt * 4 + ct] = MFMA16(Ao[kt], Bo[kt], oacc[rt * 4 + ct]);
            }
        }

        // ---- LN1 -> hr, hS ----
        LN(oacc, ln1g + el * 256, ln1b + el * 256);

        // ---- FF: 8 chunks of 128 FF cols, tS double-buffered (1 barrier/chunk) ----
        f32x4 facc[16];
        {
            const float* b2_p = b2 + el * 256;
            #pragma unroll
            for (int rt = 0; rt < 4; ++rt)
                #pragma unroll
                for (int ct = 0; ct < 4; ++ct) {
                    float bz = b2_p[nb + ct * 16 + ln];
                    f32x4 t = hr[rt * 4 + ct];
                    t[0] += bz; t[1] += bz; t[2] += bz; t[3] += bz;
                    facc[rt * 4 + ct] = t;
                }
        }
        const float* b1_p = b1 + el * 1024;
        for (int ch = 0; ch < 8; ++ch) {
            const int fb = ch * 128 + wg * 32;       // wave's 32 FF cols this chunk
            unsigned short* tC = attnS + (ch & 1) * 8704;   // [64][136] dbuf
            #pragma unroll
            for (int ct2 = 0; ct2 < 2; ++ct2) {
                bf16x8 B1c[8];
                #pragma unroll
                for (int kt = 0; kt < 8; ++kt)
                    B1c[kt] = *(const bf16x8*)(W1E + (size_t)(fb + ct2 * 16 + ln) * 256 + kt * 32 + quad * 8);
                const float bz2 = b1_p[fb + ct2 * 16 + ln];
                #pragma unroll
                for (int rt = 0; rt < 4; ++rt) {
                    bf16x8 Af[8];
                    #pragma unroll
                    for (int kt = 0; kt < 8; ++kt)
                        Af[kt] = *(const bf16x8*)&hS[(rt * 16 + ln) * 264 + kt * 32 + quad * 8];
                    f32x4 c = {bz2, bz2, bz2, bz2};
                    #pragma unroll
                    for (int kt = 0; kt < 8; ++kt) c = MFMA16(Af[kt], B1c[kt], c);
                    #pragma unroll
                    for (int i = 0; i < 4; ++i)
                        tC[(rt * 16 + quad * 4 + i) * 136 + wg * 32 + ct2 * 16 + ln]
                            = f2b(fmaxf(c[i], 0.f));
                }
            }
            __syncthreads();
            // W2 partial: K=128
            #pragma unroll
            for (int ct = 0; ct < 4; ++ct) {
                bf16x8 B2c[4];
                #pragma unroll
                for (int kt2 = 0; kt2 < 4; ++kt2)
                    B2c[kt2] = *(const bf16x8*)(W2E + (size_t)(nb + ct * 16 + ln) * 1024 + ch * 128 + kt2 * 32 + quad * 8);
                #pragma unroll
                for (int rt = 0; rt < 4; ++rt) {
                    bf16x8 At[4];
                    #pragma unroll
                    for (int kt2 = 0; kt2 < 4; ++kt2)
                        At[kt2] = *(const bf16x8*)&tC[(rt * 16 + ln) * 136 + kt2 * 32 + quad * 8];
                    #pragma unroll
                    for (int kt2 = 0; kt2 < 4; ++kt2)
                        facc[rt * 4 + ct] = MFMA16(At[kt2], B2c[kt2], facc[rt * 4 + ct]);
                }
            }
            // no barrier: next W1 writes the other tS buffer
        }

        // ---- LN2 -> hr, hS ----
        LN(facc, ln2g + el * 256, ln2b + el * 256);
    }

    // ---- pooling + Wout + weighted combine ----
    {
        #pragma unroll
        for (int ct = 0; ct < 4; ++ct) {
            float s_ = 0.f;
            #pragma unroll
            for (int rt = 0; rt < 4; ++rt)
                #pragma unroll
                for (int i = 0; i < 4; ++i) s_ += hr[rt * 4 + ct][i];
            s_ += __shfl_xor(s_, 16);
            s_ += __shfl_xor(s_, 32);
            if (quad == 0) pooledS[nb + ct * 16 + ln] = s_ * (1.f / 64.f);
        }
        __syncthreads();
        if (tid < 64) {
            const float* Wout_p = Wout + (size_t)e * (256 * 64);
            float o = bout[e * 64 + tid];
            for (int c = 0; c < 256; ++c) o += pooledS[c] * Wout_p[c * 64 + tid];
            atomicAdd(&acc_out[b * 64 + tid], wgt * o);
        }
    }
}

// ---------------------------------------------------------------------------
__global__ __launch_bounds__(64) void final_ln_kernel(
    const float* __restrict__ acc_out, const float* __restrict__ on_g,
    const float* __restrict__ on_b, float* __restrict__ out)
{
    const int b = blockIdx.x;
    const int d = threadIdx.x;
    float v = acc_out[b * 64 + d];
    float s1 = v, s2 = v * v;
    #pragma unroll
    for (int st = 1; st < 64; st <<= 1) {
        s1 += __shfl_xor(s1, st, 64);
        s2 += __shfl_xor(s2, st, 64);
    }
    float m   = s1 * (1.f / 64.f);
    float var = s2 * (1.f / 64.f) - m * m;
    float rstd = rsqrtf(var + 1e-5f);
    out[b * 64 + d] = (v - m) * rstd * on_g[d] + on_b[d];
}

// ---------------------------------------------------------------------------
extern "C" void kernel_launch(void* const* d_in, const int* in_sizes, int n_in,
                              void* d_out, int out_size, void* d_ws, size_t ws_size,
                              hipStream_t stream)
{
    (void)in_sizes; (void)n_in; (void)out_size; (void)ws_size;
    const float* x    = (const float*)d_in[0];
    const float* Win  = (const float*)d_in[1];
    const float* bin_ = (const float*)d_in[2];
    const float* Wq   = (const float*)d_in[3];
    const float* bq   = (const float*)d_in[4];
    const float* Wk   = (const float*)d_in[5];
    const float* bk   = (const float*)d_in[6];
    const float* Wv   = (const float*)d_in[7];
    const float* bv   = (const float*)d_in[8];
    const float* Wo   = (const float*)d_in[9];
    const float* bo   = (const float*)d_in[10];
    const float* ln1g = (const float*)d_in[11];
    const float* ln1b = (const float*)d_in[12];
    const float* ln2g = (const float*)d_in[13];
    const float* ln2b = (const float*)d_in[14];
    const float* W1   = (const float*)d_in[15];
    const float* b1   = (const float*)d_in[16];
    const float* W2   = (const float*)d_in[17];
    const float* b2   = (const float*)d_in[18];
    const float* Wout = (const float*)d_in[19];
    const float* bout = (const float*)d_in[20];
    const float* Wg   = (const float*)d_in[21];
    const float* bg   = (const float*)d_in[22];
    const float* Wr   = (const float*)d_in[23];
    const float* br   = (const float*)d_in[24];
    const float* on_g = (const float*)d_in[25];
    const float* on_b = (const float*)d_in[26];
    float* out = (float*)d_out;

    // workspace carve-up
    char* ws = (char*)d_ws;
    float* acc_out = (float*)ws;                         // 131,072 B
    int*   cnt     = (int*)(ws + 131072);
    int*   rlist   = (int*)(ws + 131200);                // 16,384 B
    float* wlist   = (float*)(ws + 147584);              // 16,384 B
    short* WinT    = (short*)(ws + 164096);              //   524,288 B
    short* WqT     = (short*)(ws + 688384);              // 2,097,152 B
    short* WkT     = (short*)(ws + 2785536);
    short* WvT     = (short*)(ws + 4882688);
    short* WoT     = (short*)(ws + 6979840);
    short* W1T     = (short*)(ws + 9076992);             // 8,388,608 B
    short* W2T     = (short*)(ws + 17465600);            // 8,388,608 B

    // weight transposition fp32 [R][C] -> bf16 [C][R]
    convT_kernel<<<1024, 256, 0, stream>>>(Win, WinT, 128, 256, 262144);
    convT_kernel<<<4096, 256, 0, stream>>>(Wq, WqT, 256, 256, 1048576);
    convT_kernel<<<4096, 256, 0, stream>>>(Wk, WkT, 256, 256, 1048576);
    convT_kernel<<<4096, 256, 0, stream>>>(Wv, WvT, 256, 256, 1048576);
    convT_kernel<<<4096, 256, 0, stream>>>(Wo, WoT, 256, 256, 1048576);
    convT_kernel<<<16384, 256, 0, stream>>>(W1, W1T, 256, 1024, 4194304);
    convT_kernel<<<16384, 256, 0, stream>>>(W2, W2T, 1024, 256, 4194304);

    zero_cnt_kernel<<<1, 64, 0, stream>>>(cnt);
    gate_kernel<<<512, 256, 0, stream>>>(x, Wg, bg, cnt, rlist, wlist);
    resproj_kernel<<<256, 256, 0, stream>>>(x, Wr, br, acc_out);
    expert_kernel<<<4096, 256, 0, stream>>>(x,
        WinT, bin_, WqT, bq, WkT, bk, WvT, bv, WoT, bo,
        ln1g, ln1b, ln2g, ln2b, W1T, b1, W2T, b2, Wout, bout,
        cnt, rlist, wlist, acc_out);
    final_ln_kernel<<<512, 64, 0, stream>>>(acc_out, on_g, on_b, out);
}

// Round 10
// 1015.407 us; speedup vs baseline: 1.4966x; 1.0048x over previous
//
#include <hip/hip_runtime.h>
#include <hip/hip_bf16.h>

// B=512, S=64, IN=128, DM=256, H=8, HD=32, L=2, FF=1024, DO=64, E=8, K=2, GI=8192

typedef __attribute__((ext_vector_type(8))) short bf16x8;
typedef __attribute__((ext_vector_type(4))) float f32x4;

#define DEVINL __device__ __forceinline__
#define MFMA16(a, b, c) __builtin_amdgcn_mfma_f32_16x16x32_bf16((a), (b), (c), 0, 0, 0)

DEVINL float b2f(unsigned short u) {
    unsigned int i = ((unsigned int)u) << 16;
    float f; __builtin_memcpy(&f, &i, 4); return f;
}
DEVINL unsigned short f2b(float f) {
    unsigned int i; __builtin_memcpy(&i, &f, 4);
    unsigned int r = (i + 0x7FFFu + ((i >> 16) & 1u)) >> 16;  // RTN-even
    return (unsigned short)r;
}

// ---------------------------------------------------------------------------
__global__ void zero_cnt_kernel(int* __restrict__ cnt) {
    if (threadIdx.x < 8) cnt[threadIdx.x] = 0;
}

// ---------------------------------------------------------------------------
// convT v2: tiled transpose via LDS. src fp32 [batch][R][C] -> dst bf16
// [batch][C][R]. Round 9's elementwise version read src at stride C*4B
// (4B used per 64B line, ~16x over-fetch, ~150 µs). 64x64 tile: reads
// coalesced along c, writes coalesced along r.
__global__ __launch_bounds__(256) void convT_kernel(
    const float* __restrict__ src, short* __restrict__ dst, int R, int C)
{
    const int tiles_r = R >> 6, tiles_c = C >> 6;
    int t = blockIdx.x;
    const int bM = t / (tiles_r * tiles_c);
    int rem = t - bM * (tiles_r * tiles_c);
    const int tr = rem / tiles_c, tc = rem - tr * tiles_c;
    const int r0 = tr << 6, c0 = tc << 6;
    const float* S = src + (size_t)bM * R * C;
    short* D = dst + (size_t)bM * R * C;
    __shared__ short tile[64][72];
    const int lc = threadIdx.x & 63;
    const int l0 = threadIdx.x >> 6;
    #pragma unroll
    for (int i = 0; i < 16; ++i) {
        int lr = l0 * 16 + i;
        tile[lr][lc] = (short)f2b(S[(size_t)(r0 + lr) * C + c0 + lc]);
    }
    __syncthreads();
    const int lrw = threadIdx.x & 63;
    #pragma unroll
    for (int i = 0; i < 16; ++i) {
        int lcw = l0 * 16 + i;
        D[(size_t)(c0 + lcw) * R + r0 + lrw] = tile[lrw][lcw];
    }
}

// ---------------------------------------------------------------------------
// gate: double-precision logits (stable top-2 vs numpy ref)
__global__ __launch_bounds__(256) void gate_kernel(
    const float* __restrict__ x, const float* __restrict__ Wg, const float* __restrict__ bg,
    int* __restrict__ cnt, int* __restrict__ rlist, float* __restrict__ wlist)
{
    const int b = blockIdx.x;
    const int tid = threadIdx.x;
    const int e8 = tid & 7;
    const int seg = tid >> 3;
    const float* gi = x + (size_t)b * 8192;
    double p = 0.0;
    for (int ii = 0; ii < 256; ++ii) {
        int i = seg * 256 + ii;
        p += (double)gi[i] * (double)Wg[i * 8 + e8];
    }
    p += __shfl_xor(p, 8, 64);
    p += __shfl_xor(p, 16, 64);
    p += __shfl_xor(p, 32, 64);
    __shared__ double wred[4 * 8];
    const int lane = tid & 63, w = tid >> 6;
    if (lane < 8) wred[w * 8 + lane] = p;
    __syncthreads();
    if (tid == 0) {
        double lg[8];
        for (int e = 0; e < 8; ++e)
            lg[e] = wred[e] + wred[8 + e] + wred[16 + e] + wred[24 + e] + (double)bg[e];
        int i1 = 0;
        for (int e = 1; e < 8; ++e) if (lg[e] > lg[i1]) i1 = e;
        int i2 = (i1 == 0) ? 1 : 0;
        for (int e = 0; e < 8; ++e) if (e != i1 && lg[e] > lg[i2]) i2 = e;
        double ex = exp(lg[i2] - lg[i1]);
        float w1 = (float)(1.0 / (1.0 + ex));
        float w2 = (float)(ex / (1.0 + ex));
        int p1 = atomicAdd(&cnt[i1], 1);
        rlist[i1 * 512 + p1] = b; wlist[i1 * 512 + p1] = w1;
        int p2 = atomicAdd(&cnt[i2], 1);
        rlist[i2 * 512 + p2] = b; wlist[i2 * 512 + p2] = w2;
    }
}

// ---------------------------------------------------------------------------
// resproj: 2 batch rows per block, 256 blocks
__global__ __launch_bounds__(256) void resproj_kernel(
    const float* __restrict__ x, const float* __restrict__ Wr, const float* __restrict__ br,
    float* __restrict__ acc_out)
{
    const int b0 = blockIdx.x * 2;
    const int tid = threadIdx.x;
    const int d = tid & 63;
    const int part = tid >> 6;
    float acc0 = 0.f, acc1 = 0.f;
    for (int ii = 0; ii < 2048; ++ii) {
        int i = part * 2048 + ii;
        float wv = Wr[i * 64 + d];
        acc0 += x[(size_t)b0 * 8192 + i] * wv;
        acc1 += x[(size_t)(b0 + 1) * 8192 + i] * wv;
    }
    __shared__ float rr[4][2][64];
    rr[part][0][d] = acc0;
    rr[part][1][d] = acc1;
    __syncthreads();
    if (tid < 128) {
        int k = tid >> 6, dd = tid & 63;
        float v = rr[0][k][dd] + rr[1][k][dd] + rr[2][k][dd] + rr[3][k][dd];
        acc_out[(b0 + k) * 64 + dd] = 0.1f * (v + br[dd]);
    }
}

// ---------------------------------------------------------------------------
// expert kernel — ROUND 10: round 9 (785 µs, 2 blocks/CU) still spilled
// ~102MB: at (256,2) the split is 128 arch + 128 AGPR; hp=1's K-stream has
// accum hr(64)+avr0(32)+sc(64)=160 (>128 AGPR) AND the hoisted WkB[16]=64
// arch regs -> total ~290 > 256. Fix: UN-HOIST WkB (reload 8 frags per ck
// from L2 — Wk is 16KB/head, pure L2 hits) -> peak ~228 <= 256, no spill.
// Everything else identical to round 9 (K streamed in 16-row chunks,
// V-first sc-free V GEMM, 78,336 B LDS -> 2 blocks/CU).
// XCD pin: e = blockIdx&7 so each XCD's L2 holds one expert's weight image.
__global__ __launch_bounds__(256, 2) void expert_kernel(
    const float* __restrict__ x,
    const short* __restrict__ WinT, const float* __restrict__ bin_,
    const short* __restrict__ WqT,  const float* __restrict__ bq,
    const short* __restrict__ WkT,  const float* __restrict__ bk,
    const short* __restrict__ WvT,  const float* __restrict__ bv,
    const short* __restrict__ WoT,  const float* __restrict__ bo,
    const float* __restrict__ ln1g, const float* __restrict__ ln1b,
    const float* __restrict__ ln2g, const float* __restrict__ ln2b,
    const short* __restrict__ W1T,  const float* __restrict__ b1,
    const short* __restrict__ W2T,  const float* __restrict__ b2,
    const float* __restrict__ Wout, const float* __restrict__ bout,
    const int* __restrict__ cnt, const int* __restrict__ rlist,
    const float* __restrict__ wlist, float* __restrict__ acc_out)
{
    const int e = blockIdx.x & 7;          // XCD pin
    const int s = blockIdx.x >> 3;
    if (s >= cnt[e]) return;
    const int b   = rlist[e * 512 + s];
    const float wgt = wlist[e * 512 + s];
    const int tid = threadIdx.x;
    const int lane = tid & 63;
    const int wg  = __builtin_amdgcn_readfirstlane(tid >> 6);
    const int ln = lane & 15, quad = lane >> 4;
    const int nb = wg * 64;                // wave's output-column base

    // LDS: 33,792 + 41,472 + 2,048 + 1,024 = 78,336 B -> 2 blocks/CU
    __shared__ __align__(16) unsigned short hS[64 * 264];     // residual/av/LN out
    __shared__ __align__(16) unsigned short attnS[4 * 5184];  // per-wave attn | xS | tS
    __shared__ float redS[512];                               // LN cross-wave partials
    __shared__ float pooledS[256];
    unsigned short* VTw   = attnS + wg * 5184;  // [32][72] V^T
    unsigned short* Qw    = VTw + 2304;         // [64][36] Q
    unsigned short* Kpart = VTw + 4608;         // [16][36] K chunk
    unsigned short* PSw   = Qw;                 // [64][36] P half (overlays dead Q)
    unsigned short* xS    = attnS;              // [64][136] (block-shared, P0/P1)

    // ---- P0: stage x[b] -> xS bf16 row-major ----
    {
        const float* xb = x + (size_t)b * 8192;
        #pragma unroll
        for (int i = 0; i < 32; ++i) {
            int id = tid + 256 * i;
            xS[(id >> 7) * 136 + (id & 127)] = f2b(xb[id]);
        }
    }
    __syncthreads();

    f32x4 hr[16];   // residual: wave's 64 rows x 64 cols, [rt*4+ct]

    // ---- P1: h0 = x @ Win + bin (K=128) ----
    {
        const short* BW = WinT + (size_t)e * 32768;
        const float* bp = bin_ + e * 256;
        #pragma unroll
        for (int ct = 0; ct < 4; ++ct) {
            bf16x8 Bf[4];
            #pragma unroll
            for (int kt = 0; kt < 4; ++kt)
                Bf[kt] = *(const bf16x8*)(BW + (size_t)(nb + ct * 16 + ln) * 128 + kt * 32 + quad * 8);
            const float bz = bp[nb + ct * 16 + ln];
            #pragma unroll
            for (int rt = 0; rt < 4; ++rt) {
                bf16x8 Af[4];
                #pragma unroll
                for (int kt = 0; kt < 4; ++kt)
                    Af[kt] = *(const bf16x8*)&xS[(rt * 16 + ln) * 136 + kt * 32 + quad * 8];
                f32x4 c = {bz, bz, bz, bz};
                #pragma unroll
                for (int kt = 0; kt < 4; ++kt) c = MFMA16(Af[kt], Bf[kt], c);
                hr[rt * 4 + ct] = c;
                #pragma unroll
                for (int i = 0; i < 4; ++i)
                    hS[(rt * 16 + quad * 4 + i) * 264 + nb + ct * 16 + ln] = f2b(c[i]);
            }
        }
    }
    __syncthreads();

    // LayerNorm over acc (C-layout); cross-wave via redS; writes hr + hS.
    auto LN = [&](f32x4* a, const float* g, const float* bb) {
        #pragma unroll
        for (int rt = 0; rt < 4; ++rt)
            #pragma unroll
            for (int i = 0; i < 4; ++i) {
                float s1 = 0.f, s2 = 0.f;
                #pragma unroll
                for (int ct = 0; ct < 4; ++ct) { float v = a[rt * 4 + ct][i]; s1 += v; s2 += v * v; }
                s1 += __shfl_xor(s1, 1); s1 += __shfl_xor(s1, 2);
                s1 += __shfl_xor(s1, 4); s1 += __shfl_xor(s1, 8);
                s2 += __shfl_xor(s2, 1); s2 += __shfl_xor(s2, 2);
                s2 += __shfl_xor(s2, 4); s2 += __shfl_xor(s2, 8);
                if (ln == 0) {
                    int row = rt * 16 + quad * 4 + i;
                    redS[row * 8 + wg * 2] = s1;
                    redS[row * 8 + wg * 2 + 1] = s2;
                }
            }
        __syncthreads();
        float gv[4], bv2[4];
        #pragma unroll
        for (int ct = 0; ct < 4; ++ct) { gv[ct] = g[nb + ct * 16 + ln]; bv2[ct] = bb[nb + ct * 16 + ln]; }
        #pragma unroll
        for (int rt = 0; rt < 4; ++rt)
            #pragma unroll
            for (int i = 0; i < 4; ++i) {
                int row = rt * 16 + quad * 4 + i;
                float S1 = redS[row * 8 + 0] + redS[row * 8 + 2] + redS[row * 8 + 4] + redS[row * 8 + 6];
                float S2 = redS[row * 8 + 1] + redS[row * 8 + 3] + redS[row * 8 + 5] + redS[row * 8 + 7];
                float m_ = S1 * (1.f / 256.f);
                float rstd = rsqrtf(S2 * (1.f / 256.f) - m_ * m_ + 1e-5f);
                #pragma unroll
                for (int ct = 0; ct < 4; ++ct) {
                    float v = (a[rt * 4 + ct][i] - m_) * rstd * gv[ct] + bv2[ct];
                    hr[rt * 4 + ct][i] = v;
                    hS[row * 264 + nb + ct * 16 + ln] = f2b(v);
                }
            }
        __syncthreads();
    };

    for (int l = 0; l < 2; ++l) {
        const int el = e * 2 + l;
        const short* WqE = WqT + (size_t)el * 65536;
        const short* WkE = WkT + (size_t)el * 65536;
        const short* WvE = WvT + (size_t)el * 65536;
        const short* WoE = WoT + (size_t)el * 65536;
        const short* W1E = W1T + (size_t)el * 262144;
        const short* W2E = W2T + (size_t)el * 262144;
        const float* bq_p = bq + el * 256;
        const float* bk_p = bk + el * 256;
        const float* bv_p = bv + el * 256;
        const float* bo_p = bo + el * 256;

        f32x4 avr[16];   // both heads' av: [hp*8 + rt*2 + ct2]

        // ---- QKV + attention, fully wave-private (no barriers inside) ----
        #pragma unroll
        for (int hp = 0; hp < 2; ++hp) {
            const int hb = nb + hp * 32;   // head (2wg+hp) col base

            // --- V GEMM -> VTw [32][72] (sc not live here) ---
            #pragma unroll
            for (int ct2 = 0; ct2 < 2; ++ct2) {
                bf16x8 Bq[8];
                #pragma unroll
                for (int kt = 0; kt < 8; ++kt)
                    Bq[kt] = *(const bf16x8*)(WvE + (size_t)(hb + ct2 * 16 + ln) * 256 + kt * 32 + quad * 8);
                const float bz2 = bv_p[hb + ct2 * 16 + ln];
                #pragma unroll
                for (int rt = 0; rt < 4; ++rt) {
                    bf16x8 Af[8];
                    #pragma unroll
                    for (int kt = 0; kt < 8; ++kt)
                        Af[kt] = *(const bf16x8*)&hS[(rt * 16 + ln) * 264 + kt * 32 + quad * 8];
                    f32x4 c = {bz2, bz2, bz2, bz2};
                    #pragma unroll
                    for (int kt = 0; kt < 8; ++kt) c = MFMA16(Af[kt], Bq[kt], c);
                    #pragma unroll
                    for (int i = 0; i < 4; ++i)
                        VTw[(ct2 * 16 + ln) * 72 + rt * 16 + quad * 4 + i] = f2b(c[i]);
                }
            }

            // --- Q GEMM -> Qw [64][36] ---
            #pragma unroll
            for (int ct2 = 0; ct2 < 2; ++ct2) {
                bf16x8 Bq[8];
                #pragma unroll
                for (int kt = 0; kt < 8; ++kt)
                    Bq[kt] = *(const bf16x8*)(WqE + (size_t)(hb + ct2 * 16 + ln) * 256 + kt * 32 + quad * 8);
                const float bz2 = bq_p[hb + ct2 * 16 + ln];
                #pragma unroll
                for (int rt = 0; rt < 4; ++rt) {
                    bf16x8 Af[8];
                    #pragma unroll
                    for (int kt = 0; kt < 8; ++kt)
                        Af[kt] = *(const bf16x8*)&hS[(rt * 16 + ln) * 264 + kt * 32 + quad * 8];
                    f32x4 c = {bz2, bz2, bz2, bz2};
                    #pragma unroll
                    for (int kt = 0; kt < 8; ++kt) c = MFMA16(Af[kt], Bq[kt], c);
                    #pragma unroll
                    for (int i = 0; i < 4; ++i)
                        Qw[(rt * 16 + quad * 4 + i) * 36 + ct2 * 16 + ln] = f2b(c[i]);
                }
            }

            // --- K streamed in 16-row chunks: K-chunk GEMM + QK^T partial ---
            // WkB NOT hoisted (round-10 fix): reloaded per ck from L2.
            f32x4 sc[16];
            {
                float bkz[2];
                #pragma unroll
                for (int ct2 = 0; ct2 < 2; ++ct2) bkz[ct2] = bk_p[hb + ct2 * 16 + ln];
                #pragma unroll
                for (int ck = 0; ck < 4; ++ck) {
                    // K rows ck*16..+15  (= h rows; A-frag rows ck*16+ln)
                    bf16x8 Af[8];
                    #pragma unroll
                    for (int kt = 0; kt < 8; ++kt)
                        Af[kt] = *(const bf16x8*)&hS[(ck * 16 + ln) * 264 + kt * 32 + quad * 8];
                    #pragma unroll
                    for (int ct2 = 0; ct2 < 2; ++ct2) {
                        bf16x8 WkB[8];
                        #pragma unroll
                        for (int kt = 0; kt < 8; ++kt)
                            WkB[kt] = *(const bf16x8*)(WkE + (size_t)(hb + ct2 * 16 + ln) * 256 + kt * 32 + quad * 8);
                        f32x4 c = {bkz[ct2], bkz[ct2], bkz[ct2], bkz[ct2]};
                        #pragma unroll
                        for (int kt = 0; kt < 8; ++kt) c = MFMA16(Af[kt], WkB[kt], c);
                        #pragma unroll
                        for (int i = 0; i < 4; ++i)
                            Kpart[(quad * 4 + i) * 36 + ct2 * 16 + ln] = f2b(c[i]);
                    }
                    // QK^T partial: S cols ck*16..+15 (Kpart row ln, k=quad*8)
                    bf16x8 Bk = *(const bf16x8*)&Kpart[ln * 36 + quad * 8];
                    #pragma unroll
                    for (int rt = 0; rt < 4; ++rt) {
                        bf16x8 Aq = *(const bf16x8*)&Qw[(rt * 16 + ln) * 36 + quad * 8];
                        f32x4 z = {0.f, 0.f, 0.f, 0.f};
                        sc[rt * 4 + ck] = MFMA16(Aq, Bk, z);
                    }
                }
            }

            // --- softmax, fully normalized in registers ---
            const float sscale = 0.17677669529663687f;  // 1/sqrt(32)
            #pragma unroll
            for (int t = 0; t < 16; ++t)
                #pragma unroll
                for (int i = 0; i < 4; ++i) sc[t][i] *= sscale;
            #pragma unroll
            for (int rt = 0; rt < 4; ++rt)
                #pragma unroll
                for (int i = 0; i < 4; ++i) {
                    float m_ = fmaxf(fmaxf(sc[rt * 4 + 0][i], sc[rt * 4 + 1][i]),
                                     fmaxf(sc[rt * 4 + 2][i], sc[rt * 4 + 3][i]));
                    m_ = fmaxf(m_, __shfl_xor(m_, 1));
                    m_ = fmaxf(m_, __shfl_xor(m_, 2));
                    m_ = fmaxf(m_, __shfl_xor(m_, 4));
                    m_ = fmaxf(m_, __shfl_xor(m_, 8));
                    float s_ = 0.f;
                    #pragma unroll
                    for (int ck = 0; ck < 4; ++ck) {
                        sc[rt * 4 + ck][i] = __expf(sc[rt * 4 + ck][i] - m_);
                        s_ += sc[rt * 4 + ck][i];
                    }
                    s_ += __shfl_xor(s_, 1); s_ += __shfl_xor(s_, 2);
                    s_ += __shfl_xor(s_, 4); s_ += __shfl_xor(s_, 8);
                    float inv = 1.f / s_;
                    #pragma unroll
                    for (int ck = 0; ck < 4; ++ck) sc[rt * 4 + ck][i] *= inv;
                }

            // --- two-pass P write (PSw [64][36] overlays dead Q) + PV halves ---
            // pass 0: P cols 0..31
            #pragma unroll
            for (int rt = 0; rt < 4; ++rt)
                #pragma unroll
                for (int i = 0; i < 4; ++i)
                    #pragma unroll
                    for (int ck = 0; ck < 2; ++ck)
                        PSw[(rt * 16 + quad * 4 + i) * 36 + ck * 16 + ln] = f2b(sc[rt * 4 + ck][i]);
            {
                bf16x8 Bv0[2];
                #pragma unroll
                for (int ct2 = 0; ct2 < 2; ++ct2)
                    Bv0[ct2] = *(const bf16x8*)&VTw[(ct2 * 16 + ln) * 72 + quad * 8];
                #pragma unroll
                for (int rt = 0; rt < 4; ++rt) {
                    bf16x8 Ap = *(const bf16x8*)&PSw[(rt * 16 + ln) * 36 + quad * 8];
                    #pragma unroll
                    for (int ct2 = 0; ct2 < 2; ++ct2) {
                        f32x4 z = {0.f, 0.f, 0.f, 0.f};
                        avr[hp * 8 + rt * 2 + ct2] = MFMA16(Ap, Bv0[ct2], z);
                    }
                }
            }
            // pass 1: P cols 32..63 (overwrite; in-order LDS, same-wave alias kept)
            #pragma unroll
            for (int rt = 0; rt < 4; ++rt)
                #pragma unroll
                for (int i = 0; i < 4; ++i)
                    #pragma unroll
                    for (int ck = 2; ck < 4; ++ck)
                        PSw[(rt * 16 + quad * 4 + i) * 36 + (ck - 2) * 16 + ln] = f2b(sc[rt * 4 + ck][i]);
            {
                bf16x8 Bv1[2];
                #pragma unroll
                for (int ct2 = 0; ct2 < 2; ++ct2)
                    Bv1[ct2] = *(const bf16x8*)&VTw[(ct2 * 16 + ln) * 72 + 32 + quad * 8];
                #pragma unroll
                for (int rt = 0; rt < 4; ++rt) {
                    bf16x8 Ap = *(const bf16x8*)&PSw[(rt * 16 + ln) * 36 + quad * 8];
                    #pragma unroll
                    for (int ct2 = 0; ct2 < 2; ++ct2)
                        avr[hp * 8 + rt * 2 + ct2] = MFMA16(Ap, Bv1[ct2], avr[hp * 8 + rt * 2 + ct2]);
                }
            }
        }

        __syncthreads();   // all waves done reading hS(h)
        // write av (wave's exact 64-col strip) -> hS
        #pragma unroll
        for (int hp = 0; hp < 2; ++hp)
            #pragma unroll
            for (int rt = 0; rt < 4; ++rt)
                #pragma unroll
                for (int ct2 = 0; ct2 < 2; ++ct2)
                    #pragma unroll
                    for (int i = 0; i < 4; ++i)
                        hS[(rt * 16 + quad * 4 + i) * 264 + nb + hp * 32 + ct2 * 16 + ln]
                            = f2b(avr[hp * 8 + rt * 2 + ct2][i]);
        __syncthreads();

        // ---- O-proj: oacc = h + bo + av @ Wo (K=256) ----
        f32x4 oacc[16];
        #pragma unroll
        for (int rt = 0; rt < 4; ++rt)
            #pragma unroll
            for (int ct = 0; ct < 4; ++ct) {
                float bz = bo_p[nb + ct * 16 + ln];
                f32x4 t = hr[rt * 4 + ct];
                t[0] += bz; t[1] += bz; t[2] += bz; t[3] += bz;
                oacc[rt * 4 + ct] = t;
            }
        #pragma unroll
        for (int ct = 0; ct < 4; ++ct) {
            bf16x8 Bo[8];
            #pragma unroll
            for (int kt = 0; kt < 8; ++kt)
                Bo[kt] = *(const bf16x8*)(WoE + (size_t)(nb + ct * 16 + ln) * 256 + kt * 32 + quad * 8);
            #pragma unroll
            for (int rt = 0; rt < 4; ++rt) {
                bf16x8 Ao[8];
                #pragma unroll
                for (int kt = 0; kt < 8; ++kt)
                    Ao[kt] = *(const bf16x8*)&hS[(rt * 16 + ln) * 264 + kt * 32 + quad * 8];
                #pragma unroll
                for (int kt = 0; kt < 8; ++kt)
                    oacc[rt * 4 + ct] = MFMA16(Ao[kt], Bo[kt], oacc[rt * 4 + ct]);
            }
        }

        // ---- LN1 -> hr, hS ----
        LN(oacc, ln1g + el * 256, ln1b + el * 256);

        // ---- FF: 8 chunks of 128 FF cols, tS double-buffered (1 barrier/chunk) ----
        f32x4 facc[16];
        {
            const float* b2_p = b2 + el * 256;
            #pragma unroll
            for (int rt = 0; rt < 4; ++rt)
                #pragma unroll
                for (int ct = 0; ct < 4; ++ct) {
                    float bz = b2_p[nb + ct * 16 + ln];
                    f32x4 t = hr[rt * 4 + ct];
                    t[0] += bz; t[1] += bz; t[2] += bz; t[3] += bz;
                    facc[rt * 4 + ct] = t;
                }
        }
        const float* b1_p = b1 + el * 1024;
        for (int ch = 0; ch < 8; ++ch) {
            const int fb = ch * 128 + wg * 32;       // wave's 32 FF cols this chunk
            unsigned short* tC = attnS + (ch & 1) * 8704;   // [64][136] dbuf
            #pragma unroll
            for (int ct2 = 0; ct2 < 2; ++ct2) {
                bf16x8 B1c[8];
                #pragma unroll
                for (int kt = 0; kt < 8; ++kt)
                    B1c[kt] = *(const bf16x8*)(W1E + (size_t)(fb + ct2 * 16 + ln) * 256 + kt * 32 + quad * 8);
                const float bz2 = b1_p[fb + ct2 * 16 + ln];
                #pragma unroll
                for (int rt = 0; rt < 4; ++rt) {
                    bf16x8 Af[8];
                    #pragma unroll
                    for (int kt = 0; kt < 8; ++kt)
                        Af[kt] = *(const bf16x8*)&hS[(rt * 16 + ln) * 264 + kt * 32 + quad * 8];
                    f32x4 c = {bz2, bz2, bz2, bz2};
                    #pragma unroll
                    for (int kt = 0; kt < 8; ++kt) c = MFMA16(Af[kt], B1c[kt], c);
                    #pragma unroll
                    for (int i = 0; i < 4; ++i)
                        tC[(rt * 16 + quad * 4 + i) * 136 + wg * 32 + ct2 * 16 + ln]
                            = f2b(fmaxf(c[i], 0.f));
                }
            }
            __syncthreads();
            // W2 partial: K=128
            #pragma unroll
            for (int ct = 0; ct < 4; ++ct) {
                bf16x8 B2c[4];
                #pragma unroll
                for (int kt2 = 0; kt2 < 4; ++kt2)
                    B2c[kt2] = *(const bf16x8*)(W2E + (size_t)(nb + ct * 16 + ln) * 1024 + ch * 128 + kt2 * 32 + quad * 8);
                #pragma unroll
                for (int rt = 0; rt < 4; ++rt) {
                    bf16x8 At[4];
                    #pragma unroll
                    for (int kt2 = 0; kt2 < 4; ++kt2)
                        At[kt2] = *(const bf16x8*)&tC[(rt * 16 + ln) * 136 + kt2 * 32 + quad * 8];
                    #pragma unroll
                    for (int kt2 = 0; kt2 < 4; ++kt2)
                        facc[rt * 4 + ct] = MFMA16(At[kt2], B2c[kt2], facc[rt * 4 + ct]);
                }
            }
            // no barrier: next W1 writes the other tS buffer
        }

        // ---- LN2 -> hr, hS ----
        LN(facc, ln2g + el * 256, ln2b + el * 256);
    }

    // ---- pooling + Wout + weighted combine ----
    {
        #pragma unroll
        for (int ct = 0; ct < 4; ++ct) {
            float s_ = 0.f;
            #pragma unroll
            for (int rt = 0; rt < 4; ++rt)
                #pragma unroll
                for (int i = 0; i < 4; ++i) s_ += hr[rt * 4 + ct][i];
            s_ += __shfl_xor(s_, 16);
            s_ += __shfl_xor(s_, 32);
            if (quad == 0) pooledS[nb + ct * 16 + ln] = s_ * (1.f / 64.f);
        }
        __syncthreads();
        if (tid < 64) {
            const float* Wout_p = Wout + (size_t)e * (256 * 64);
            float o = bout[e * 64 + tid];
            for (int c = 0; c < 256; ++c) o += pooledS[c] * Wout_p[c * 64 + tid];
            atomicAdd(&acc_out[b * 64 + tid], wgt * o);
        }
    }
}

// ---------------------------------------------------------------------------
__global__ __launch_bounds__(64) void final_ln_kernel(
    const float* __restrict__ acc_out, const float* __restrict__ on_g,
    const float* __restrict__ on_b, float* __restrict__ out)
{
    const int b = blockIdx.x;
    const int d = threadIdx.x;
    float v = acc_out[b * 64 + d];
    float s1 = v, s2 = v * v;
    #pragma unroll
    for (int st = 1; st < 64; st <<= 1) {
        s1 += __shfl_xor(s1, st, 64);
        s2 += __shfl_xor(s2, st, 64);
    }
    float m   = s1 * (1.f / 64.f);
    float var = s2 * (1.f / 64.f) - m * m;
    float rstd = rsqrtf(var + 1e-5f);
    out[b * 64 + d] = (v - m) * rstd * on_g[d] + on_b[d];
}

// ---------------------------------------------------------------------------
extern "C" void kernel_launch(void* const* d_in, const int* in_sizes, int n_in,
                              void* d_out, int out_size, void* d_ws, size_t ws_size,
                              hipStream_t stream)
{
    (void)in_sizes; (void)n_in; (void)out_size; (void)ws_size;
    const float* x    = (const float*)d_in[0];
    const float* Win  = (const float*)d_in[1];
    const float* bin_ = (const float*)d_in[2];
    const float* Wq   = (const float*)d_in[3];
    const float* bq   = (const float*)d_in[4];
    const float* Wk   = (const float*)d_in[5];
    const float* bk   = (const float*)d_in[6];
    const float* Wv   = (const float*)d_in[7];
    const float* bv   = (const float*)d_in[8];
    const float* Wo   = (const float*)d_in[9];
    const float* bo   = (const float*)d_in[10];
    const float* ln1g = (const float*)d_in[11];
    const float* ln1b = (const float*)d_in[12];
    const float* ln2g = (const float*)d_in[13];
    const float* ln2b = (const float*)d_in[14];
    const float* W1   = (const float*)d_in[15];
    const float* b1   = (const float*)d_in[16];
    const float* W2   = (const float*)d_in[17];
    const float* b2   = (const float*)d_in[18];
    const float* Wout = (const float*)d_in[19];
    const float* bout = (const float*)d_in[20];
    const float* Wg   = (const float*)d_in[21];
    const float* bg   = (const float*)d_in[22];
    const float* Wr   = (const float*)d_in[23];
    const float* br   = (const float*)d_in[24];
    const float* on_g = (const float*)d_in[25];
    const float* on_b = (const float*)d_in[26];
    float* out = (float*)d_out;

    // workspace carve-up
    char* ws = (char*)d_ws;
    float* acc_out = (float*)ws;                         // 131,072 B
    int*   cnt     = (int*)(ws + 131072);
    int*   rlist   = (int*)(ws + 131200);                // 16,384 B
    float* wlist   = (float*)(ws + 147584);              // 16,384 B
    short* WinT    = (short*)(ws + 164096);              //   524,288 B
    short* WqT     = (short*)(ws + 688384);              // 2,097,152 B
    short* WkT     = (short*)(ws + 2785536);
    short* WvT     = (short*)(ws + 4882688);
    short* WoT     = (short*)(ws + 6979840);
    short* W1T     = (short*)(ws + 9076992);             // 8,388,608 B
    short* W2T     = (short*)(ws + 17465600);            // 8,388,608 B

    // weight transposition fp32 [R][C] -> bf16 [C][R] (tiled, coalesced)
    convT_kernel<<<64, 256, 0, stream>>>(Win, WinT, 128, 256);     // 8*2*4
    convT_kernel<<<256, 256, 0, stream>>>(Wq, WqT, 256, 256);      // 16*4*4
    convT_kernel<<<256, 256, 0, stream>>>(Wk, WkT, 256, 256);
    convT_kernel<<<256, 256, 0, stream>>>(Wv, WvT, 256, 256);
    convT_kernel<<<256, 256, 0, stream>>>(Wo, WoT, 256, 256);
    convT_kernel<<<1024, 256, 0, stream>>>(W1, W1T, 256, 1024);    // 16*4*16
    convT_kernel<<<1024, 256, 0, stream>>>(W2, W2T, 1024, 256);    // 16*16*4

    zero_cnt_kernel<<<1, 64, 0, stream>>>(cnt);
    gate_kernel<<<512, 256, 0, stream>>>(x, Wg, bg, cnt, rlist, wlist);
    resproj_kernel<<<256, 256, 0, stream>>>(x, Wr, br, acc_out);
    expert_kernel<<<4096, 256, 0, stream>>>(x,
        WinT, bin_, WqT, bq, WkT, bk, WvT, bv, WoT, bo,
        ln1g, ln1b, ln2g, ln2b, W1T, b1, W2T, b2, Wout, bout,
        cnt, rlist, wlist, acc_out);
    final_ln_kernel<<<512, 64, 0, stream>>>(acc_out, on_g, on_b, out);
}